// Round 24
// baseline (343.774 us; speedup 1.0000x reference)
//
#include <hip/hip_runtime.h>
#include <cstdint>

// ---------------------------------------------------------------------------
// BinaryNet forward, MFMA edition.
//  * binary_tanh(bn2d(conv+b)) == threshold on exact integer conv value.
//  * binary conv == i8 GEMM via mfma_i32_32x32x32_i8 -> exact integers.
//  * integer thresholds T (verified with f64 fma) -> binarize bit-identical.
//  * stats: 256-bucket privatized atomics + parallel bucket reduction.
//  * pool layers: in-register 2x2 (min,max) packed int32.
//  * round-24 changes (both occupancy levers, pattern-matched to round-23's
//    mconv win):
//    - L2 mconv SH 16->8: LDS 49KB->27KB lifts the 3-blocks/CU LDS cap to
//      the attribute's 4 blocks/CU (+33% waves).
//    - conv1_p2 wpe(2,2) -> launch_bounds(256,4): round-22's f32-bounds
//      rewrite shrank p2's live set (~100 regs) under the 128 budget.
//      Revert trigger: p2 FETCH > 10MB (spill fingerprint).
// ---------------------------------------------------------------------------

typedef int v4i __attribute__((ext_vector_type(4)));
typedef int v16i __attribute__((ext_vector_type(16)));

#define NBKT 256       // stats buckets
#define SSTR 1664      // stats words per bucket (2*832)

// ---- weight pack: sign(+-1) i8 + stats zeroing -----------------------------
__global__ void __launch_bounds__(256) pack8(const float* __restrict__ w2,
                                             const float* __restrict__ w3,
                                             const float* __restrict__ w4,
                                             const float* __restrict__ w5,
                                             const float* __restrict__ w6,
                                             int8_t* __restrict__ w8,
                                             unsigned long long* __restrict__ stats) {
  const int idx = blockIdx.x * 256 + threadIdx.x;
  if (idx < NBKT * SSTR) stats[idx] = 0ull;
  const float* w; int CiL, e; int8_t* dst;
  if (idx < 36864)        { w = w2; CiL = 64;  e = idx;          dst = w8; }
  else if (idx < 110592)  { w = w3; CiL = 64;  e = idx - 36864;  dst = w8 + 36864; }
  else if (idx < 258048)  { w = w4; CiL = 128; e = idx - 110592; dst = w8 + 110592; }
  else if (idx < 552960)  { w = w5; CiL = 128; e = idx - 258048; dst = w8 + 258048; }
  else if (idx < 1142784) { w = w6; CiL = 256; e = idx - 552960; dst = w8 + 552960; }
  else return;
  const int WDk = CiL / 32;
  const int b = e & 15;
  const int l31 = (e >> 4) & 31;
  const int hi = (e >> 9) & 1;
  const int kc = (e >> 10) % WDk;
  const int tap = (e / (1024 * WDk)) % 9;
  const int cb = e / (9216 * WDk);
  const int co = cb * 32 + l31;
  const int ci = kc * 32 + hi * 16 + b;
  dst[e] = (w[((size_t)co * CiL + ci) * 9 + tap] >= 0.f) ? (int8_t)1 : (int8_t)-1;
}

// ---- conv1 pass 1: f32 conv, 2 channels per window pass, f64 stats ---------
__global__ void __launch_bounds__(256, 6) conv1_p1(const float* __restrict__ x,
                                                   const float* __restrict__ w1,
                                                   double2* __restrict__ part) {
  __shared__ float ximg[3][34][34];
  __shared__ float wl[16][28];
  __shared__ double pS[16][4], pQ[16][4];
  const int tid = threadIdx.x, n = blockIdx.x, cg = blockIdx.y;
  for (int i = tid; i < 3 * 34 * 34; i += 256) ((float*)ximg)[i] = 0.f;
  for (int i = tid; i < 16 * 27; i += 256) wl[i / 27][i % 27] = w1[cg * 432 + i];
  __syncthreads();
  const float* xb = x + (size_t)n * 3072;
  for (int i = tid; i < 3072; i += 256) {
    const int c = i >> 10, p = i & 1023;
    ximg[c][(p >> 5) + 1][(p & 31) + 1] = xb[i];
  }
  __syncthreads();
  const int h = tid >> 3, w0 = (tid & 7) * 4;
  const int lane = tid & 63, wv = tid >> 6;
  for (int c = 0; c < 16; c += 2) {
    float4 wa4[7], wb4[7];
#pragma unroll
    for (int i = 0; i < 7; i++) {
      wa4[i] = *(const float4*)&wl[c][i * 4];
      wb4[i] = *(const float4*)&wl[c + 1][i * 4];
    }
    const float* wfa = (const float*)wa4;
    const float* wfb = (const float*)wb4;
    float accA[4] = {0.f, 0.f, 0.f, 0.f};
    float accB[4] = {0.f, 0.f, 0.f, 0.f};
#pragma unroll
    for (int ic = 0; ic < 3; ic++)
#pragma unroll
      for (int ky = 0; ky < 3; ky++) {
        float xr[6];
#pragma unroll
        for (int t = 0; t < 6; t++) xr[t] = ximg[ic][h + ky][w0 + t];
#pragma unroll
        for (int kx = 0; kx < 3; kx++) {
          const float wga = wfa[ic * 9 + ky * 3 + kx];
          const float wgb = wfb[ic * 9 + ky * 3 + kx];
#pragma unroll
          for (int j = 0; j < 4; j++) {
            accA[j] = fmaf(xr[j + kx], wga, accA[j]);
            accB[j] = fmaf(xr[j + kx], wgb, accB[j]);
          }
        }
      }
    // stats, same per-channel f64 order as always
    double s = (double)accA[0] + accA[1] + accA[2] + accA[3];
    double q = (double)accA[0] * accA[0] + (double)accA[1] * accA[1] +
               (double)accA[2] * accA[2] + (double)accA[3] * accA[3];
    double s2 = (double)accB[0] + accB[1] + accB[2] + accB[3];
    double q2 = (double)accB[0] * accB[0] + (double)accB[1] * accB[1] +
                (double)accB[2] * accB[2] + (double)accB[3] * accB[3];
#pragma unroll
    for (int off = 32; off; off >>= 1) {
      s += __shfl_down(s, off);
      q += __shfl_down(q, off);
      s2 += __shfl_down(s2, off);
      q2 += __shfl_down(q2, off);
    }
    if (lane == 0) {
      pS[c][wv] = s;      pQ[c][wv] = q;
      pS[c + 1][wv] = s2; pQ[c + 1][wv] = q2;
    }
  }
  __syncthreads();
  if (tid < 16) {
    const double S = pS[tid][0] + pS[tid][1] + pS[tid][2] + pS[tid][3];
    const double Q = pQ[tid][0] + pQ[tid][1] + pQ[tid][2] + pQ[tid][3];
    part[(size_t)(cg * 16 + tid) * 512 + n] = make_double2(S, Q);
  }
}

// ---- conv1_fin: parallel tree reduction over the 512 per-image partials ----
__global__ void __launch_bounds__(256) conv1_fin(const double2* __restrict__ part,
                                                 const float* __restrict__ g,
                                                 const float* __restrict__ be,
                                                 const float* __restrict__ w1,
                                                 double2* __restrict__ thr,
                                                 double* __restrict__ te) {
  __shared__ double sS[4], sQ[4];
  const int c = blockIdx.x;  // 64 blocks
  const int t = threadIdx.x;
  const double2 a = part[(size_t)c * 512 + t];
  const double2 b = part[(size_t)c * 512 + 256 + t];
  double S = a.x + b.x, Q = a.y + b.y;
#pragma unroll
  for (int off = 32; off; off >>= 1) {
    S += __shfl_down(S, off);
    Q += __shfl_down(Q, off);
  }
  if ((t & 63) == 0) { sS[t >> 6] = S; sQ[t >> 6] = Q; }
  __syncthreads();
  if (t != 0) return;
  S = sS[0] + sS[1] + sS[2] + sS[3];
  Q = sQ[0] + sQ[1] + sQ[2] + sQ[3];
  const double Nel = 512.0 * 1024.0;
  const double mu = S / Nel, var = Q / Nel - mu * mu;
  const double r = 1.0 / sqrt(var + 1e-4);
  const double al = (double)g[c] * r;
  const double bt = (double)be[c] - al * mu;
  thr[c] = make_double2(al, bt);
  double ws = 0.0;
  for (int k = 0; k < 27; k++) ws += fabs((double)w1[c * 27 + k]);
  te[c] = fabs(al) * 27.0 * 5.9604644775390625e-08 * ws * 1.25;
}

// ---- conv1 pass 2: f32 conv + f32 certified bounds + exact-f64 fallback ----
__global__ void __launch_bounds__(256, 4)
conv1_p2(const float* __restrict__ x, const float* __restrict__ w1,
         const double2* __restrict__ thr, const double* __restrict__ te,
         uint16_t* __restrict__ stg) {
  __shared__ float ximg[3][34][34];
  __shared__ float wl[16][28];
  __shared__ float bndLo[16], bndHi[16];
  __shared__ uint32_t bflag[16];   // bit0 = decision when v>=hi, bit1 = when v<=lo
  __shared__ float smx[4];
  const int tid = threadIdx.x, n = blockIdx.x, cg = blockIdx.y;
  for (int i = tid; i < 3 * 34 * 34; i += 256) ((float*)ximg)[i] = 0.f;
  for (int i = tid; i < 16 * 27; i += 256) wl[i / 27][i % 27] = w1[cg * 432 + i];
  __syncthreads();
  const float* xb = x + (size_t)n * 3072;
  float mx = 0.f;
  for (int i = tid; i < 3072; i += 256) {
    const int c = i >> 10, p = i & 1023;
    const float v = xb[i];
    ximg[c][(p >> 5) + 1][(p & 31) + 1] = v;
    mx = fmaxf(mx, fabsf(v));
  }
  const int lane = tid & 63, wv = tid >> 6;
#pragma unroll
  for (int off = 32; off; off >>= 1) mx = fmaxf(mx, __shfl_xor(mx, off));
  if (lane == 0) smx[wv] = mx;
  __syncthreads();
  const double Xmax = (double)fmaxf(fmaxf(smx[0], smx[1]), fmaxf(smx[2], smx[3]));
  if (tid < 16) {
    const double2 ab = thr[cg * 16 + tid];
    const double ef = te[cg * 16 + tid] * Xmax;
    float lf, hf;
    uint32_t fl;
    if (ab.x > 0.0 || ab.x < 0.0) {
      const double e1 = (ef - ab.y) / ab.x;
      const double e2 = (-ef - ab.y) / ab.x;
      const double bLo = fmin(e1, e2), bHi = fmax(e1, e2);
      hf = (float)(bHi + fabs(bHi) * 1e-6 + 1e-25);
      lf = (float)(bLo - fabs(bLo) * 1e-6 - 1e-25);
      const uint32_t dhi = (ab.x > 0.0) ? 1u : 0u;
      fl = dhi | ((1u - dhi) << 1);   // dlo = !dhi
    } else {
      hf = -3.4e38f;
      lf = -3.4e38f;
      fl = (ab.y >= 0.0) ? 1u : 0u;
    }
    bndLo[tid] = lf;
    bndHi[tid] = hf;
    bflag[tid] = fl;
  }
  __syncthreads();
  const int h = tid >> 3, w0 = (tid & 7) * 4;
  float win[3][3][6];
#pragma unroll
  for (int ic = 0; ic < 3; ic++)
#pragma unroll
    for (int ky = 0; ky < 3; ky++)
#pragma unroll
      for (int t = 0; t < 6; t++) win[ic][ky][t] = ximg[ic][h + ky][w0 + t];
  uint32_t wbits[4] = {0u, 0u, 0u, 0u};
  for (int c = 0; c < 16; c++) {
    float4 wv4[7];
#pragma unroll
    for (int i = 0; i < 7; i++) wv4[i] = *(const float4*)&wl[c][i * 4];
    const float* wf = (const float*)wv4;
    float acc[4] = {0.f, 0.f, 0.f, 0.f};
#pragma unroll
    for (int ic = 0; ic < 3; ic++)
#pragma unroll
      for (int ky = 0; ky < 3; ky++)
#pragma unroll
        for (int kx = 0; kx < 3; kx++) {
          const float wgt = wf[ic * 9 + ky * 3 + kx];
#pragma unroll
          for (int j = 0; j < 4; j++) acc[j] = fmaf(win[ic][ky][j + kx], wgt, acc[j]);
        }
    const float lf = bndLo[c], hf = bndHi[c];
    const uint32_t fl = bflag[c];
#pragma unroll
    for (int j = 0; j < 4; j++) {
      const float v = acc[j];
      uint32_t bit;
      if (v >= hf) {
        bit = fl & 1u;
      } else if (v <= lf) {
        bit = (fl >> 1) & 1u;
      } else {
        // rare: re-derive exactly (same fma order as the all-f64 chain)
        double a64 = 0.0;
        for (int k = 0; k < 27; k++) {
          const int ic = k / 9, rr = k % 9, ky = rr / 3, kx = rr % 3;
          a64 = fma((double)ximg[ic][h + ky][w0 + j + kx], (double)wl[c][k], a64);
        }
        const double2 ab = thr[cg * 16 + c];
        bit = (fma(ab.x, a64, ab.y) >= 0.0) ? 1u : 0u;
      }
      if (bit) wbits[j] |= 1u << c;
    }
  }
  // packed 8B store, planar [cg][np]: coalesced (consecutive lanes -> 8B apart)
  const int p0 = h * 32 + w0;
  uint2 pkd;
  pkd.x = (wbits[0] & 0xFFFFu) | (wbits[1] << 16);
  pkd.y = (wbits[2] & 0xFFFFu) | (wbits[3] << 16);
  *(uint2*)&stg[(size_t)cg * 524288 + (size_t)n * 1024 + p0] = pkd;
}

// ---- zip 4 staging planes into A1 [np][2] words (c = wd*32 + half*16 + j) --
__global__ void __launch_bounds__(256) a1merge(const uint16_t* __restrict__ stg,
                                               uint32_t* __restrict__ A1) {
  const int idx = blockIdx.x * 256 + threadIdx.x;  // 2 np per thread
  const int np = idx * 2;
  if (np >= 512 * 1024) return;
  const uint32_t a0 = *(const uint32_t*)&stg[0 * 524288 + np];
  const uint32_t a1 = *(const uint32_t*)&stg[1 * 524288 + np];
  const uint32_t a2 = *(const uint32_t*)&stg[2 * 524288 + np];
  const uint32_t a3 = *(const uint32_t*)&stg[3 * 524288 + np];
  uint4 o;
  o.x = (a0 & 0xFFFFu) | (a1 << 16);
  o.y = (a2 & 0xFFFFu) | (a3 << 16);
  o.z = (a0 >> 16) | (a1 & 0xFFFF0000u);
  o.w = (a2 >> 16) | (a3 & 0xFFFF0000u);
  *(uint4*)&A1[(size_t)np * 2] = o;
}

// ---- MFMA binary conv v6: CHK tuned per-layer, 4 waves/EU ------------------
template <int H, int W, int SH, int Ci, int CO, int WN, int MG, int POOL>
__global__ void __launch_bounds__(256, 4)
mconv(const uint32_t* __restrict__ Ain, const int8_t* __restrict__ w8,
      short* __restrict__ raw, unsigned long long* __restrict__ stats) {
  constexpr int WD = Ci / 32, Wp = W + 2, Cs = Ci + 16, P = H * W;
  constexpr int STRIPS = H / SH;
  constexpr int MT = SH * W / 32;
  constexpr int WM = 4 / WN;
  constexpr int MTW = MT / WM;
  constexpr int NG = MTW / MG;
  constexpr int CHK = (MG == 4) ? 1 : 2;   // bound live set: bf + acc <= ~120
  constexpr int NCH = WD / CHK;
  constexpr int IMGB = (SH + 2) * Wp * Cs;
  constexpr int Wo = W / 2, Po = (H / 2) * Wo;
  static_assert(NG >= 1 && MTW == NG * MG && WD % CHK == 0, "bad geometry");
  __shared__ __align__(16) uint32_t img[IMGB / 4];
  const int tid = threadIdx.x;
  const int n = blockIdx.x / STRIPS, s = blockIdx.x % STRIPS;
  int* __restrict__ mm = (int*)raw;

  for (int i = tid; i < IMGB / 4; i += 256) img[i] = 0u;
  __syncthreads();
  constexpr int ROWW = W * WD;
  for (int i = tid; i < (SH + 2) * ROWW; i += 256) {
    const int lr = i / ROWW;
    const int h = s * SH - 1 + lr;
    if (h < 0 || h >= H) continue;
    const int rem = i % ROWW;
    const int wpx = rem / WD, d = rem % WD;
    const uint32_t bits = Ain[((size_t)n * P + h * W + wpx) * WD + d];
    uint32_t* dst = img + ((lr * Wp + wpx + 1) * Cs) / 4 + d * 8;
#pragma unroll
    for (int nb2 = 0; nb2 < 8; nb2++) {
      const uint32_t t = (((bits >> (4 * nb2)) & 0xFu) * 0x00204081u) & 0x01010101u;
      dst[nb2] = 0x01010101u + (t ^ 0x01010101u) * 0xFEu;
    }
  }
  __syncthreads();

  const int wv = tid >> 6, lane = tid & 63, l31 = lane & 31, hi = lane >> 5;
  const int nb = wv % WN, ms = wv / WN;
  const int cb = blockIdx.y * WN + nb;
  const int co = cb * 32 + l31;
  const int8_t* wbl = w8 + (size_t)cb * 9 * WD * 1024 + (size_t)lane * 16;
  const char* imgb = (const char*)img;
  int sA = 0, qA = 0;
#pragma unroll 1
  for (int mg = 0; mg < NG; mg++) {
    v16i acc[MG];
#pragma unroll
    for (int m = 0; m < MG; m++)
      acc[m] = (v16i){0, 0, 0, 0, 0, 0, 0, 0, 0, 0, 0, 0, 0, 0, 0, 0};
    int ab[MG];
#pragma unroll
    for (int m = 0; m < MG; m++) {
      const int mt = ms * MTW + mg * MG + m;
      const int pp = mt * 32 + l31;
      ab[m] = ((pp / W) * Wp + (pp % W)) * Cs + hi * 16;
    }
#pragma unroll 1
    for (int ch = 0; ch < NCH; ++ch) {
      v4i bf[9 * CHK];
#pragma unroll
      for (int t9 = 0; t9 < 9; t9++)
#pragma unroll
        for (int c = 0; c < CHK; c++)
          bf[t9 * CHK + c] =
              *(const v4i*)(wbl + (size_t)(t9 * WD + ch * CHK + c) * 1024);
#pragma unroll
      for (int tap = 0; tap < 9; tap++) {
        const int toff = ((tap / 3) * Wp + (tap % 3)) * Cs;
#pragma unroll
        for (int c = 0; c < CHK; c++)
#pragma unroll
          for (int m = 0; m < MG; m++) {
            const v4i a =
                *(const v4i*)(imgb + ab[m] + toff + (ch * CHK + c) * 32);
            acc[m] = __builtin_amdgcn_mfma_i32_32x32x32_i8(a, bf[tap * CHK + c],
                                                           acc[m], 0, 0, 0);
          }
      }
    }
#pragma unroll
    for (int m = 0; m < MG; m++)
#pragma unroll
      for (int r = 0; r < 16; r++) {
        const int v = acc[m][r];
        sA += v;
        qA += v * v;
      }
    if constexpr (POOL) {
      if constexpr (W == 32) {
#pragma unroll
        for (int mp = 0; mp < MG / 2; mp++) {
          const int mt0 = ms * MTW + mg * MG + 2 * mp;
          const int ho = (s * SH + mt0) >> 1;
#pragma unroll
          for (int r = 0; r < 16; r += 2) {
            const int v00 = acc[2 * mp][r], v01 = acc[2 * mp][r + 1];
            const int v10 = acc[2 * mp + 1][r], v11 = acc[2 * mp + 1][r + 1];
            const int mn = min(min(v00, v01), min(v10, v11));
            const int mxv = max(max(v00, v01), max(v10, v11));
            const int wo = ((r & 3) + 8 * (r >> 2) + 4 * hi) >> 1;
            mm[((size_t)n * Po + ho * Wo + wo) * CO + co] =
                (int)(((uint32_t)(uint16_t)(short)mxv << 16) |
                      (uint32_t)(uint16_t)(short)mn);
          }
        }
      } else if constexpr (W == 16) {
#pragma unroll
        for (int m = 0; m < MG; m++) {
          const int mt = ms * MTW + mg * MG + m;
          const int ho = (s * SH) / 2 + mt;
#pragma unroll
          for (int r = 0; r < 8; r += 2) {
            const int v00 = acc[m][r], v01 = acc[m][r + 1];
            const int v10 = acc[m][r + 8], v11 = acc[m][r + 9];
            const int mn = min(min(v00, v01), min(v10, v11));
            const int mxv = max(max(v00, v01), max(v10, v11));
            const int wo = ((r & 3) + 8 * (r >> 2) + 4 * hi) >> 1;
            mm[((size_t)n * Po + ho * Wo + wo) * CO + co] =
                (int)(((uint32_t)(uint16_t)(short)mxv << 16) |
                      (uint32_t)(uint16_t)(short)mn);
          }
        }
      } else {
#pragma unroll
        for (int m = 0; m < MG; m++) {
          const int mt = ms * MTW + mg * MG + m;
#pragma unroll
          for (int rb = 0; rb < 2; rb++)
#pragma unroll
            for (int rr = 0; rr < 4; rr += 2) {
              const int r = rb * 8 + rr;
              const int v00 = acc[m][r], v01 = acc[m][r + 1];
              const int v10 = acc[m][r + 4], v11 = acc[m][r + 5];
              const int mn = min(min(v00, v01), min(v10, v11));
              const int mxv = max(max(v00, v01), max(v10, v11));
              const int ho = (s * SH) / 2 + 2 * mt + rb;
              const int wo = (rr + 4 * hi) >> 1;
              mm[((size_t)n * Po + ho * Wo + wo) * CO + co] =
                  (int)(((uint32_t)(uint16_t)(short)mxv << 16) |
                        (uint32_t)(uint16_t)(short)mn);
            }
        }
      }
    } else {
#pragma unroll
      for (int m = 0; m < MG; m++) {
        const int mt = ms * MTW + mg * MG + m;
#pragma unroll
        for (int r = 0; r < 16; r++) {
          const int row = (r & 3) + 8 * (r >> 2) + 4 * hi;
          const int p = s * SH * W + mt * 32 + row;
          raw[((size_t)n * P + p) * CO + co] = (short)acc[m][r];
        }
      }
    }
  }
  sA += __shfl_xor(sA, 32);
  qA += __shfl_xor(qA, 32);
  if (hi == 0) {
    const size_t bkt = (size_t)(blockIdx.x & (NBKT - 1)) * SSTR;
    atomicAdd(&stats[bkt + 2 * co], (unsigned long long)(long long)sA);
    atomicAdd(&stats[bkt + 2 * co + 1], (unsigned long long)(long long)qA);
  }
}

// ---- BN threshold: PARALLEL bucket reduction (exact integer sums) ----------
__global__ void __launch_bounds__(256) bin_fin(const unsigned long long* __restrict__ stats,
                                               const float* __restrict__ g,
                                               const float* __restrict__ be,
                                               int2* __restrict__ thri, int Co,
                                               double Nel) {
  __shared__ long long sS[4], sQ[4];
  const int c = blockIdx.x;
  const int t = threadIdx.x;
  long long Si = (long long)stats[(size_t)t * SSTR + 2 * c];
  long long Qi = (long long)stats[(size_t)t * SSTR + 2 * c + 1];
#pragma unroll
  for (int off = 32; off; off >>= 1) {
    Si += __shfl_down(Si, off);
    Qi += __shfl_down(Qi, off);
  }
  if ((t & 63) == 0) { sS[t >> 6] = Si; sQ[t >> 6] = Qi; }
  __syncthreads();
  if (t != 0) return;
  const double S = (double)(sS[0] + sS[1] + sS[2] + sS[3]);
  const double Q = (double)(sQ[0] + sQ[1] + sQ[2] + sQ[3]);
  const double mu = S / Nel, var = Q / Nel - mu * mu;
  const double rr = 1.0 / sqrt(var + 1e-4);
  const double al = (double)g[c] * rr;
  const double bt = (double)be[c] - al * mu;
  int T, dir;
  if (al > 0.0) {
    dir = 1;
    const double tt = -bt / al;
    if (tt >= 6000.0) T = 6000;
    else if (tt <= -6000.0) T = -6000;
    else {
      T = (int)ceil(tt);
      if (fma(al, (double)(T - 1), bt) >= 0.0) T -= 1;
      else if (fma(al, (double)T, bt) < 0.0) T += 1;
    }
  } else if (al < 0.0) {
    dir = 0;
    const double tt = -bt / al;
    if (tt >= 6000.0) T = 6000;
    else if (tt <= -6000.0) T = -6000;
    else {
      T = (int)floor(tt);
      if (fma(al, (double)(T + 1), bt) >= 0.0) T += 1;
      else if (fma(al, (double)T, bt) < 0.0) T -= 1;
    }
  } else {
    dir = 1;
    T = (bt >= 0.0) ? -6000 : 6000;
  }
  thri[c] = make_int2(T, dir);
  (void)Co;
}

// ---- binarize (no pool): raw [np][CO] -> packed A [np][CO/32] ----
template <int P, int CO>
__global__ void __launch_bounds__(256) binz_r(const short* __restrict__ raw,
                                              const int2* __restrict__ thr,
                                              uint32_t* __restrict__ Aout) {
  constexpr int WDo = CO / 32;
  const int idx = blockIdx.x * 256 + threadIdx.x;
  if (idx >= 512 * P * WDo) return;
  const int np = idx / WDo, wd = idx % WDo;
  const short* p = raw + (size_t)np * CO + wd * 32;
  v4i q[4];
#pragma unroll
  for (int t = 0; t < 4; t++) q[t] = __builtin_nontemporal_load((const v4i*)p + t);
  const short* sv = (const short*)q;
  uint32_t word = 0;
#pragma unroll
  for (int j = 0; j < 32; j++) {
    const int v = sv[j];
    const int2 td = thr[wd * 32 + j];
    word |= (uint32_t)(td.y ? (v >= td.x) : (v <= td.x)) << j;
  }
  Aout[idx] = word;
}

// ---- pooled binarize from packed (min,max) planes [npo][CO] ----
template <int Po, int CO>
__global__ void __launch_bounds__(256) binpool_mm(const int* __restrict__ mm,
                                                  const int2* __restrict__ thr,
                                                  uint32_t* __restrict__ Aout) {
  constexpr int WDo = CO / 32;
  const int idx = blockIdx.x * 256 + threadIdx.x;
  if (idx >= 512 * Po * WDo) return;
  const int np = idx / WDo, wd = idx % WDo;
  const int* p = mm + (size_t)np * CO + wd * 32;
  v4i q[8];
#pragma unroll
  for (int t = 0; t < 8; t++) q[t] = __builtin_nontemporal_load((const v4i*)p + t);
  const int* iv = (const int*)q;
  uint32_t word = 0;
#pragma unroll
  for (int j = 0; j < 32; j++) {
    const int v = iv[j];
    const int mn = (short)(v & 0xFFFF), mx = (short)(v >> 16);
    const int2 td = thr[wd * 32 + j];
    const bool b = td.y ? (mx >= td.x) : (mn <= td.x);
    word |= (uint32_t)b << j;
  }
  Aout[idx] = word;
}

// ---- head: avgpool(4x4) + binary FC (exact in f32) ----
__global__ void __launch_bounds__(64) head_kern(const uint32_t* __restrict__ A6,
                                                const float* __restrict__ fcw,
                                                const float* __restrict__ fcb,
                                                float* __restrict__ fcout) {
  __shared__ uint32_t aw[128];
  __shared__ float feat[256];
  const int n = blockIdx.x, t = threadIdx.x;
  for (int i = t; i < 128; i += 64) aw[i] = A6[(size_t)n * 128 + i];
  __syncthreads();
#pragma unroll
  for (int k = 0; k < 4; k++) {
    const int c = t * 4 + k;
    const int wd = c >> 5, sh = c & 31;
    int cnt = 0;
#pragma unroll
    for (int pos = 0; pos < 16; pos++) cnt += (aw[pos * 8 + wd] >> sh) & 1;
    feat[c] = (float)(cnt - 8) * 0.125f;  // exact
  }
  __syncthreads();
  if (t < 10) {
    float acc = 0.f;  // all partial sums exactly representable
    for (int c = 0; c < 256; c++) acc += (fcw[t * 256 + c] >= 0.f ? feat[c] : -feat[c]);
    fcout[n * 10 + t] = acc + fcb[t];
  }
}

// ---- bn1d over batch: one block, wave per output channel ----
__global__ void __launch_bounds__(640) bn1d_kern(const float* __restrict__ fcout,
                                                 const float* __restrict__ g7,
                                                 const float* __restrict__ be7,
                                                 float* __restrict__ out) {
  const int t = threadIdx.x, o = t >> 6, lane = t & 63;
  double s = 0.0, q = 0.0;
  float v[8];
#pragma unroll
  for (int i = 0; i < 8; i++) {
    v[i] = fcout[(lane + 64 * i) * 10 + o];
    s += v[i];
    q += (double)v[i] * v[i];
  }
#pragma unroll
  for (int off = 32; off; off >>= 1) {
    s += __shfl_down(s, off);
    q += __shfl_down(q, off);
  }
  s = __shfl(s, 0);
  q = __shfl(q, 0);
  const double mu = s / 512.0, var = q / 512.0 - mu * mu;
  const double r = 1.0 / sqrt(var + 1e-5);
  const double al = (double)g7[o] * r;
  const double bt = (double)be7[o] - al * mu;
#pragma unroll
  for (int i = 0; i < 8; i++) out[(lane + 64 * i) * 10 + o] = (float)fma(al, (double)v[i], bt);
}

extern "C" void kernel_launch(void* const* d_in, const int* in_sizes, int n_in,
                              void* d_out, int out_size, void* d_ws, size_t ws_size,
                              hipStream_t stream) {
  const float* x = (const float*)d_in[0];
  const float* w1 = (const float*)d_in[1];
  const float* g1 = (const float*)d_in[3];
  const float* be1 = (const float*)d_in[4];
  const float* w2 = (const float*)d_in[5];
  const float* g2 = (const float*)d_in[7];
  const float* be2 = (const float*)d_in[8];
  const float* w3 = (const float*)d_in[9];
  const float* g3 = (const float*)d_in[11];
  const float* be3 = (const float*)d_in[12];
  const float* w4 = (const float*)d_in[13];
  const float* g4 = (const float*)d_in[15];
  const float* be4 = (const float*)d_in[16];
  const float* w5 = (const float*)d_in[17];
  const float* g5 = (const float*)d_in[19];
  const float* be5 = (const float*)d_in[20];
  const float* w6 = (const float*)d_in[21];
  const float* g6 = (const float*)d_in[23];
  const float* be6 = (const float*)d_in[24];
  const float* fcw = (const float*)d_in[25];
  const float* fcb = (const float*)d_in[26];
  const float* g7 = (const float*)d_in[27];
  const float* be7 = (const float*)d_in[28];
  float* out = (float*)d_out;

  char* ws = (char*)d_ws;
  size_t off = 0;
  auto take = [&](size_t bytes) -> char* {
    char* p = ws + off;
    off = (off + bytes + 255) & ~(size_t)255;
    return p;
  };
  uint32_t* A1 = (uint32_t*)take((size_t)512 * 1024 * 2 * 4);
  uint32_t* A2 = (uint32_t*)take((size_t)512 * 256 * 2 * 4);
  uint32_t* A3 = (uint32_t*)take((size_t)512 * 256 * 4 * 4);
  uint32_t* A4 = (uint32_t*)take((size_t)512 * 64 * 4 * 4);
  uint32_t* A5 = (uint32_t*)take((size_t)512 * 64 * 8 * 4);
  uint32_t* A6 = (uint32_t*)take((size_t)512 * 16 * 8 * 4);
  int8_t* w8 = (int8_t*)take((size_t)1142784);
  double2* part1 = (double2*)take((size_t)64 * 512 * 16);
  unsigned long long* stats = (unsigned long long*)take((size_t)NBKT * SSTR * 8);
  double2* thrD = (double2*)take((size_t)64 * 16);
  double* teD = (double*)take((size_t)64 * 8);
  int2* thri = (int2*)take((size_t)832 * 8);
  float* fcout = (float*)take((size_t)512 * 10 * 4);
  short* raw = (short*)take((size_t)64 * 512 * 1024 * 2);
  (void)ws_size; (void)in_sizes; (void)n_in; (void)out_size;

  pack8<<<4464, 256, 0, stream>>>(w2, w3, w4, w5, w6, w8, stats);

  conv1_p1<<<dim3(512, 4), 256, 0, stream>>>(x, w1, part1);
  conv1_fin<<<64, 256, 0, stream>>>(part1, g1, be1, w1, thrD, teD);
  // p2 writes planar staging (aliases raw: raw unused until L2 mconv)
  conv1_p2<<<dim3(512, 4), 256, 0, stream>>>(x, w1, thrD, teD, (uint16_t*)raw);
  a1merge<<<1024, 256, 0, stream>>>((const uint16_t*)raw, A1);

  // L2 (pool): 32x32, Ci=64, CO=64; SH=8 -> LDS 27KB, 4 strips, 2048 blocks
  mconv<32, 32, 8, 64, 64, 2, 4, 1><<<dim3(2048, 1), 256, 0, stream>>>(A1, w8, raw, stats + 0);
  bin_fin<<<64, 256, 0, stream>>>(stats + 0, g2, be2, thri + 0, 64, 512.0 * 1024.0);
  binpool_mm<256, 64><<<1024, 256, 0, stream>>>((const int*)raw, thri + 0, A2);

  // L3: 16x16, Ci=64, CO=128 (no pool)
  mconv<16, 16, 8, 64, 128, 4, 4, 0><<<dim3(1024, 1), 256, 0, stream>>>(A2, w8 + 36864, raw, stats + 128);
  bin_fin<<<128, 256, 0, stream>>>(stats + 128, g3, be3, thri + 64, 128, 512.0 * 256.0);
  binz_r<256, 128><<<2048, 256, 0, stream>>>(raw, thri + 64, A3);

  // L4 (pool): 16x16, Ci=128, CO=128 -> mm [npo][128]
  mconv<16, 16, 8, 128, 128, 4, 4, 1><<<dim3(1024, 1), 256, 0, stream>>>(A3, w8 + 110592, raw, stats + 384);
  bin_fin<<<128, 256, 0, stream>>>(stats + 384, g4, be4, thri + 192, 128, 512.0 * 256.0);
  binpool_mm<64, 128><<<512, 256, 0, stream>>>((const int*)raw, thri + 192, A4);

  // L5: 8x8, Ci=128, CO=256 (no pool)
  mconv<8, 8, 8, 128, 256, 4, 2, 0><<<dim3(512, 2), 256, 0, stream>>>(A4, w8 + 258048, raw, stats + 640);
  bin_fin<<<256, 256, 0, stream>>>(stats + 640, g5, be5, thri + 320, 256, 512.0 * 64.0);
  binz_r<64, 256><<<1024, 256, 0, stream>>>(raw, thri + 320, A5);

  // L6 (pool): 8x8, Ci=256, CO=256 -> mm [npo][256]
  mconv<8, 8, 8, 256, 256, 4, 2, 1><<<dim3(512, 2), 256, 0, stream>>>(A5, w8 + 552960, raw, stats + 1152);
  bin_fin<<<256, 256, 0, stream>>>(stats + 1152, g6, be6, thri + 576, 256, 512.0 * 64.0);
  binpool_mm<16, 256><<<256, 256, 0, stream>>>((const int*)raw, thri + 576, A6);

  head_kern<<<512, 64, 0, stream>>>(A6, fcw, fcb, fcout);
  bn1d_kern<<<1, 640, 0, stream>>>(fcout, g7, be7, out);
}

// Round 25
// 338.035 us; speedup vs baseline: 1.0170x; 1.0170x over previous
//
#include <hip/hip_runtime.h>
#include <cstdint>

// ---------------------------------------------------------------------------
// BinaryNet forward, MFMA edition.
//  * binary_tanh(bn2d(conv+b)) == threshold on exact integer conv value.
//  * binary conv == i8 GEMM via mfma_i32_32x32x32_i8 -> exact integers.
//  * integer thresholds T (verified with f64 fma) -> binarize bit-identical.
//  * stats: 256-bucket privatized atomics + parallel bucket reduction.
//  * pool layers: in-register 2x2 (min,max) packed int32.
//  * round-25: keep L2 SH=8 (round-24 win, ~-10us); revert p2 to wpe(2,2)
//    (round-24's (256,4) spilled: VGPR 64, FETCH 45MB/WRITE 88MB, +28us).
//    p2 config space now exhausted: only wpe(2,2) avoids spill/re-read.
// ---------------------------------------------------------------------------

typedef int v4i __attribute__((ext_vector_type(4)));
typedef int v16i __attribute__((ext_vector_type(16)));

#define NBKT 256       // stats buckets
#define SSTR 1664      // stats words per bucket (2*832)

// ---- weight pack: sign(+-1) i8 + stats zeroing -----------------------------
__global__ void __launch_bounds__(256) pack8(const float* __restrict__ w2,
                                             const float* __restrict__ w3,
                                             const float* __restrict__ w4,
                                             const float* __restrict__ w5,
                                             const float* __restrict__ w6,
                                             int8_t* __restrict__ w8,
                                             unsigned long long* __restrict__ stats) {
  const int idx = blockIdx.x * 256 + threadIdx.x;
  if (idx < NBKT * SSTR) stats[idx] = 0ull;
  const float* w; int CiL, e; int8_t* dst;
  if (idx < 36864)        { w = w2; CiL = 64;  e = idx;          dst = w8; }
  else if (idx < 110592)  { w = w3; CiL = 64;  e = idx - 36864;  dst = w8 + 36864; }
  else if (idx < 258048)  { w = w4; CiL = 128; e = idx - 110592; dst = w8 + 110592; }
  else if (idx < 552960)  { w = w5; CiL = 128; e = idx - 258048; dst = w8 + 258048; }
  else if (idx < 1142784) { w = w6; CiL = 256; e = idx - 552960; dst = w8 + 552960; }
  else return;
  const int WDk = CiL / 32;
  const int b = e & 15;
  const int l31 = (e >> 4) & 31;
  const int hi = (e >> 9) & 1;
  const int kc = (e >> 10) % WDk;
  const int tap = (e / (1024 * WDk)) % 9;
  const int cb = e / (9216 * WDk);
  const int co = cb * 32 + l31;
  const int ci = kc * 32 + hi * 16 + b;
  dst[e] = (w[((size_t)co * CiL + ci) * 9 + tap] >= 0.f) ? (int8_t)1 : (int8_t)-1;
}

// ---- conv1 pass 1: f32 conv, 2 channels per window pass, f64 stats ---------
__global__ void __launch_bounds__(256, 6) conv1_p1(const float* __restrict__ x,
                                                   const float* __restrict__ w1,
                                                   double2* __restrict__ part) {
  __shared__ float ximg[3][34][34];
  __shared__ float wl[16][28];
  __shared__ double pS[16][4], pQ[16][4];
  const int tid = threadIdx.x, n = blockIdx.x, cg = blockIdx.y;
  for (int i = tid; i < 3 * 34 * 34; i += 256) ((float*)ximg)[i] = 0.f;
  for (int i = tid; i < 16 * 27; i += 256) wl[i / 27][i % 27] = w1[cg * 432 + i];
  __syncthreads();
  const float* xb = x + (size_t)n * 3072;
  for (int i = tid; i < 3072; i += 256) {
    const int c = i >> 10, p = i & 1023;
    ximg[c][(p >> 5) + 1][(p & 31) + 1] = xb[i];
  }
  __syncthreads();
  const int h = tid >> 3, w0 = (tid & 7) * 4;
  const int lane = tid & 63, wv = tid >> 6;
  for (int c = 0; c < 16; c += 2) {
    float4 wa4[7], wb4[7];
#pragma unroll
    for (int i = 0; i < 7; i++) {
      wa4[i] = *(const float4*)&wl[c][i * 4];
      wb4[i] = *(const float4*)&wl[c + 1][i * 4];
    }
    const float* wfa = (const float*)wa4;
    const float* wfb = (const float*)wb4;
    float accA[4] = {0.f, 0.f, 0.f, 0.f};
    float accB[4] = {0.f, 0.f, 0.f, 0.f};
#pragma unroll
    for (int ic = 0; ic < 3; ic++)
#pragma unroll
      for (int ky = 0; ky < 3; ky++) {
        float xr[6];
#pragma unroll
        for (int t = 0; t < 6; t++) xr[t] = ximg[ic][h + ky][w0 + t];
#pragma unroll
        for (int kx = 0; kx < 3; kx++) {
          const float wga = wfa[ic * 9 + ky * 3 + kx];
          const float wgb = wfb[ic * 9 + ky * 3 + kx];
#pragma unroll
          for (int j = 0; j < 4; j++) {
            accA[j] = fmaf(xr[j + kx], wga, accA[j]);
            accB[j] = fmaf(xr[j + kx], wgb, accB[j]);
          }
        }
      }
    // stats, same per-channel f64 order as always
    double s = (double)accA[0] + accA[1] + accA[2] + accA[3];
    double q = (double)accA[0] * accA[0] + (double)accA[1] * accA[1] +
               (double)accA[2] * accA[2] + (double)accA[3] * accA[3];
    double s2 = (double)accB[0] + accB[1] + accB[2] + accB[3];
    double q2 = (double)accB[0] * accB[0] + (double)accB[1] * accB[1] +
                (double)accB[2] * accB[2] + (double)accB[3] * accB[3];
#pragma unroll
    for (int off = 32; off; off >>= 1) {
      s += __shfl_down(s, off);
      q += __shfl_down(q, off);
      s2 += __shfl_down(s2, off);
      q2 += __shfl_down(q2, off);
    }
    if (lane == 0) {
      pS[c][wv] = s;      pQ[c][wv] = q;
      pS[c + 1][wv] = s2; pQ[c + 1][wv] = q2;
    }
  }
  __syncthreads();
  if (tid < 16) {
    const double S = pS[tid][0] + pS[tid][1] + pS[tid][2] + pS[tid][3];
    const double Q = pQ[tid][0] + pQ[tid][1] + pQ[tid][2] + pQ[tid][3];
    part[(size_t)(cg * 16 + tid) * 512 + n] = make_double2(S, Q);
  }
}

// ---- conv1_fin: parallel tree reduction over the 512 per-image partials ----
__global__ void __launch_bounds__(256) conv1_fin(const double2* __restrict__ part,
                                                 const float* __restrict__ g,
                                                 const float* __restrict__ be,
                                                 const float* __restrict__ w1,
                                                 double2* __restrict__ thr,
                                                 double* __restrict__ te) {
  __shared__ double sS[4], sQ[4];
  const int c = blockIdx.x;  // 64 blocks
  const int t = threadIdx.x;
  const double2 a = part[(size_t)c * 512 + t];
  const double2 b = part[(size_t)c * 512 + 256 + t];
  double S = a.x + b.x, Q = a.y + b.y;
#pragma unroll
  for (int off = 32; off; off >>= 1) {
    S += __shfl_down(S, off);
    Q += __shfl_down(Q, off);
  }
  if ((t & 63) == 0) { sS[t >> 6] = S; sQ[t >> 6] = Q; }
  __syncthreads();
  if (t != 0) return;
  S = sS[0] + sS[1] + sS[2] + sS[3];
  Q = sQ[0] + sQ[1] + sQ[2] + sQ[3];
  const double Nel = 512.0 * 1024.0;
  const double mu = S / Nel, var = Q / Nel - mu * mu;
  const double r = 1.0 / sqrt(var + 1e-4);
  const double al = (double)g[c] * r;
  const double bt = (double)be[c] - al * mu;
  thr[c] = make_double2(al, bt);
  double ws = 0.0;
  for (int k = 0; k < 27; k++) ws += fabs((double)w1[c * 27 + k]);
  te[c] = fabs(al) * 27.0 * 5.9604644775390625e-08 * ws * 1.25;
}

// ---- conv1 pass 2: f32 conv + f32 certified bounds + exact-f64 fallback ----
__global__ void __launch_bounds__(256)
__attribute__((amdgpu_waves_per_eu(2, 2)))
conv1_p2(const float* __restrict__ x, const float* __restrict__ w1,
         const double2* __restrict__ thr, const double* __restrict__ te,
         uint16_t* __restrict__ stg) {
  __shared__ float ximg[3][34][34];
  __shared__ float wl[16][28];
  __shared__ float bndLo[16], bndHi[16];
  __shared__ uint32_t bflag[16];   // bit0 = decision when v>=hi, bit1 = when v<=lo
  __shared__ float smx[4];
  const int tid = threadIdx.x, n = blockIdx.x, cg = blockIdx.y;
  for (int i = tid; i < 3 * 34 * 34; i += 256) ((float*)ximg)[i] = 0.f;
  for (int i = tid; i < 16 * 27; i += 256) wl[i / 27][i % 27] = w1[cg * 432 + i];
  __syncthreads();
  const float* xb = x + (size_t)n * 3072;
  float mx = 0.f;
  for (int i = tid; i < 3072; i += 256) {
    const int c = i >> 10, p = i & 1023;
    const float v = xb[i];
    ximg[c][(p >> 5) + 1][(p & 31) + 1] = v;
    mx = fmaxf(mx, fabsf(v));
  }
  const int lane = tid & 63, wv = tid >> 6;
#pragma unroll
  for (int off = 32; off; off >>= 1) mx = fmaxf(mx, __shfl_xor(mx, off));
  if (lane == 0) smx[wv] = mx;
  __syncthreads();
  const double Xmax = (double)fmaxf(fmaxf(smx[0], smx[1]), fmaxf(smx[2], smx[3]));
  if (tid < 16) {
    const double2 ab = thr[cg * 16 + tid];
    const double ef = te[cg * 16 + tid] * Xmax;
    float lf, hf;
    uint32_t fl;
    if (ab.x > 0.0 || ab.x < 0.0) {
      const double e1 = (ef - ab.y) / ab.x;
      const double e2 = (-ef - ab.y) / ab.x;
      const double bLo = fmin(e1, e2), bHi = fmax(e1, e2);
      hf = (float)(bHi + fabs(bHi) * 1e-6 + 1e-25);
      lf = (float)(bLo - fabs(bLo) * 1e-6 - 1e-25);
      const uint32_t dhi = (ab.x > 0.0) ? 1u : 0u;
      fl = dhi | ((1u - dhi) << 1);   // dlo = !dhi
    } else {
      hf = -3.4e38f;
      lf = -3.4e38f;
      fl = (ab.y >= 0.0) ? 1u : 0u;
    }
    bndLo[tid] = lf;
    bndHi[tid] = hf;
    bflag[tid] = fl;
  }
  __syncthreads();
  const int h = tid >> 3, w0 = (tid & 7) * 4;
  float win[3][3][6];
#pragma unroll
  for (int ic = 0; ic < 3; ic++)
#pragma unroll
    for (int ky = 0; ky < 3; ky++)
#pragma unroll
      for (int t = 0; t < 6; t++) win[ic][ky][t] = ximg[ic][h + ky][w0 + t];
  uint32_t wbits[4] = {0u, 0u, 0u, 0u};
  for (int c = 0; c < 16; c++) {
    float4 wv4[7];
#pragma unroll
    for (int i = 0; i < 7; i++) wv4[i] = *(const float4*)&wl[c][i * 4];
    const float* wf = (const float*)wv4;
    float acc[4] = {0.f, 0.f, 0.f, 0.f};
#pragma unroll
    for (int ic = 0; ic < 3; ic++)
#pragma unroll
      for (int ky = 0; ky < 3; ky++)
#pragma unroll
        for (int kx = 0; kx < 3; kx++) {
          const float wgt = wf[ic * 9 + ky * 3 + kx];
#pragma unroll
          for (int j = 0; j < 4; j++) acc[j] = fmaf(win[ic][ky][j + kx], wgt, acc[j]);
        }
    const float lf = bndLo[c], hf = bndHi[c];
    const uint32_t fl = bflag[c];
#pragma unroll
    for (int j = 0; j < 4; j++) {
      const float v = acc[j];
      uint32_t bit;
      if (v >= hf) {
        bit = fl & 1u;
      } else if (v <= lf) {
        bit = (fl >> 1) & 1u;
      } else {
        // rare: re-derive exactly (same fma order as the all-f64 chain)
        double a64 = 0.0;
        for (int k = 0; k < 27; k++) {
          const int ic = k / 9, rr = k % 9, ky = rr / 3, kx = rr % 3;
          a64 = fma((double)ximg[ic][h + ky][w0 + j + kx], (double)wl[c][k], a64);
        }
        const double2 ab = thr[cg * 16 + c];
        bit = (fma(ab.x, a64, ab.y) >= 0.0) ? 1u : 0u;
      }
      if (bit) wbits[j] |= 1u << c;
    }
  }
  // packed 8B store, planar [cg][np]: coalesced (consecutive lanes -> 8B apart)
  const int p0 = h * 32 + w0;
  uint2 pkd;
  pkd.x = (wbits[0] & 0xFFFFu) | (wbits[1] << 16);
  pkd.y = (wbits[2] & 0xFFFFu) | (wbits[3] << 16);
  *(uint2*)&stg[(size_t)cg * 524288 + (size_t)n * 1024 + p0] = pkd;
}

// ---- zip 4 staging planes into A1 [np][2] words (c = wd*32 + half*16 + j) --
__global__ void __launch_bounds__(256) a1merge(const uint16_t* __restrict__ stg,
                                               uint32_t* __restrict__ A1) {
  const int idx = blockIdx.x * 256 + threadIdx.x;  // 2 np per thread
  const int np = idx * 2;
  if (np >= 512 * 1024) return;
  const uint32_t a0 = *(const uint32_t*)&stg[0 * 524288 + np];
  const uint32_t a1 = *(const uint32_t*)&stg[1 * 524288 + np];
  const uint32_t a2 = *(const uint32_t*)&stg[2 * 524288 + np];
  const uint32_t a3 = *(const uint32_t*)&stg[3 * 524288 + np];
  uint4 o;
  o.x = (a0 & 0xFFFFu) | (a1 << 16);
  o.y = (a2 & 0xFFFFu) | (a3 << 16);
  o.z = (a0 >> 16) | (a1 & 0xFFFF0000u);
  o.w = (a2 >> 16) | (a3 & 0xFFFF0000u);
  *(uint4*)&A1[(size_t)np * 2] = o;
}

// ---- MFMA binary conv v6: CHK tuned per-layer, 4 waves/EU ------------------
template <int H, int W, int SH, int Ci, int CO, int WN, int MG, int POOL>
__global__ void __launch_bounds__(256, 4)
mconv(const uint32_t* __restrict__ Ain, const int8_t* __restrict__ w8,
      short* __restrict__ raw, unsigned long long* __restrict__ stats) {
  constexpr int WD = Ci / 32, Wp = W + 2, Cs = Ci + 16, P = H * W;
  constexpr int STRIPS = H / SH;
  constexpr int MT = SH * W / 32;
  constexpr int WM = 4 / WN;
  constexpr int MTW = MT / WM;
  constexpr int NG = MTW / MG;
  constexpr int CHK = (MG == 4) ? 1 : 2;   // bound live set: bf + acc <= ~120
  constexpr int NCH = WD / CHK;
  constexpr int IMGB = (SH + 2) * Wp * Cs;
  constexpr int Wo = W / 2, Po = (H / 2) * Wo;
  static_assert(NG >= 1 && MTW == NG * MG && WD % CHK == 0, "bad geometry");
  __shared__ __align__(16) uint32_t img[IMGB / 4];
  const int tid = threadIdx.x;
  const int n = blockIdx.x / STRIPS, s = blockIdx.x % STRIPS;
  int* __restrict__ mm = (int*)raw;

  for (int i = tid; i < IMGB / 4; i += 256) img[i] = 0u;
  __syncthreads();
  constexpr int ROWW = W * WD;
  for (int i = tid; i < (SH + 2) * ROWW; i += 256) {
    const int lr = i / ROWW;
    const int h = s * SH - 1 + lr;
    if (h < 0 || h >= H) continue;
    const int rem = i % ROWW;
    const int wpx = rem / WD, d = rem % WD;
    const uint32_t bits = Ain[((size_t)n * P + h * W + wpx) * WD + d];
    uint32_t* dst = img + ((lr * Wp + wpx + 1) * Cs) / 4 + d * 8;
#pragma unroll
    for (int nb2 = 0; nb2 < 8; nb2++) {
      const uint32_t t = (((bits >> (4 * nb2)) & 0xFu) * 0x00204081u) & 0x01010101u;
      dst[nb2] = 0x01010101u + (t ^ 0x01010101u) * 0xFEu;
    }
  }
  __syncthreads();

  const int wv = tid >> 6, lane = tid & 63, l31 = lane & 31, hi = lane >> 5;
  const int nb = wv % WN, ms = wv / WN;
  const int cb = blockIdx.y * WN + nb;
  const int co = cb * 32 + l31;
  const int8_t* wbl = w8 + (size_t)cb * 9 * WD * 1024 + (size_t)lane * 16;
  const char* imgb = (const char*)img;
  int sA = 0, qA = 0;
#pragma unroll 1
  for (int mg = 0; mg < NG; mg++) {
    v16i acc[MG];
#pragma unroll
    for (int m = 0; m < MG; m++)
      acc[m] = (v16i){0, 0, 0, 0, 0, 0, 0, 0, 0, 0, 0, 0, 0, 0, 0, 0};
    int ab[MG];
#pragma unroll
    for (int m = 0; m < MG; m++) {
      const int mt = ms * MTW + mg * MG + m;
      const int pp = mt * 32 + l31;
      ab[m] = ((pp / W) * Wp + (pp % W)) * Cs + hi * 16;
    }
#pragma unroll 1
    for (int ch = 0; ch < NCH; ++ch) {
      v4i bf[9 * CHK];
#pragma unroll
      for (int t9 = 0; t9 < 9; t9++)
#pragma unroll
        for (int c = 0; c < CHK; c++)
          bf[t9 * CHK + c] =
              *(const v4i*)(wbl + (size_t)(t9 * WD + ch * CHK + c) * 1024);
#pragma unroll
      for (int tap = 0; tap < 9; tap++) {
        const int toff = ((tap / 3) * Wp + (tap % 3)) * Cs;
#pragma unroll
        for (int c = 0; c < CHK; c++)
#pragma unroll
          for (int m = 0; m < MG; m++) {
            const v4i a =
                *(const v4i*)(imgb + ab[m] + toff + (ch * CHK + c) * 32);
            acc[m] = __builtin_amdgcn_mfma_i32_32x32x32_i8(a, bf[tap * CHK + c],
                                                           acc[m], 0, 0, 0);
          }
      }
    }
#pragma unroll
    for (int m = 0; m < MG; m++)
#pragma unroll
      for (int r = 0; r < 16; r++) {
        const int v = acc[m][r];
        sA += v;
        qA += v * v;
      }
    if constexpr (POOL) {
      if constexpr (W == 32) {
#pragma unroll
        for (int mp = 0; mp < MG / 2; mp++) {
          const int mt0 = ms * MTW + mg * MG + 2 * mp;
          const int ho = (s * SH + mt0) >> 1;
#pragma unroll
          for (int r = 0; r < 16; r += 2) {
            const int v00 = acc[2 * mp][r], v01 = acc[2 * mp][r + 1];
            const int v10 = acc[2 * mp + 1][r], v11 = acc[2 * mp + 1][r + 1];
            const int mn = min(min(v00, v01), min(v10, v11));
            const int mxv = max(max(v00, v01), max(v10, v11));
            const int wo = ((r & 3) + 8 * (r >> 2) + 4 * hi) >> 1;
            mm[((size_t)n * Po + ho * Wo + wo) * CO + co] =
                (int)(((uint32_t)(uint16_t)(short)mxv << 16) |
                      (uint32_t)(uint16_t)(short)mn);
          }
        }
      } else if constexpr (W == 16) {
#pragma unroll
        for (int m = 0; m < MG; m++) {
          const int mt = ms * MTW + mg * MG + m;
          const int ho = (s * SH) / 2 + mt;
#pragma unroll
          for (int r = 0; r < 8; r += 2) {
            const int v00 = acc[m][r], v01 = acc[m][r + 1];
            const int v10 = acc[m][r + 8], v11 = acc[m][r + 9];
            const int mn = min(min(v00, v01), min(v10, v11));
            const int mxv = max(max(v00, v01), max(v10, v11));
            const int wo = ((r & 3) + 8 * (r >> 2) + 4 * hi) >> 1;
            mm[((size_t)n * Po + ho * Wo + wo) * CO + co] =
                (int)(((uint32_t)(uint16_t)(short)mxv << 16) |
                      (uint32_t)(uint16_t)(short)mn);
          }
        }
      } else {
#pragma unroll
        for (int m = 0; m < MG; m++) {
          const int mt = ms * MTW + mg * MG + m;
#pragma unroll
          for (int rb = 0; rb < 2; rb++)
#pragma unroll
            for (int rr = 0; rr < 4; rr += 2) {
              const int r = rb * 8 + rr;
              const int v00 = acc[m][r], v01 = acc[m][r + 1];
              const int v10 = acc[m][r + 4], v11 = acc[m][r + 5];
              const int mn = min(min(v00, v01), min(v10, v11));
              const int mxv = max(max(v00, v01), max(v10, v11));
              const int ho = (s * SH) / 2 + 2 * mt + rb;
              const int wo = (rr + 4 * hi) >> 1;
              mm[((size_t)n * Po + ho * Wo + wo) * CO + co] =
                  (int)(((uint32_t)(uint16_t)(short)mxv << 16) |
                        (uint32_t)(uint16_t)(short)mn);
            }
        }
      }
    } else {
#pragma unroll
      for (int m = 0; m < MG; m++) {
        const int mt = ms * MTW + mg * MG + m;
#pragma unroll
        for (int r = 0; r < 16; r++) {
          const int row = (r & 3) + 8 * (r >> 2) + 4 * hi;
          const int p = s * SH * W + mt * 32 + row;
          raw[((size_t)n * P + p) * CO + co] = (short)acc[m][r];
        }
      }
    }
  }
  sA += __shfl_xor(sA, 32);
  qA += __shfl_xor(qA, 32);
  if (hi == 0) {
    const size_t bkt = (size_t)(blockIdx.x & (NBKT - 1)) * SSTR;
    atomicAdd(&stats[bkt + 2 * co], (unsigned long long)(long long)sA);
    atomicAdd(&stats[bkt + 2 * co + 1], (unsigned long long)(long long)qA);
  }
}

// ---- BN threshold: PARALLEL bucket reduction (exact integer sums) ----------
__global__ void __launch_bounds__(256) bin_fin(const unsigned long long* __restrict__ stats,
                                               const float* __restrict__ g,
                                               const float* __restrict__ be,
                                               int2* __restrict__ thri, int Co,
                                               double Nel) {
  __shared__ long long sS[4], sQ[4];
  const int c = blockIdx.x;
  const int t = threadIdx.x;
  long long Si = (long long)stats[(size_t)t * SSTR + 2 * c];
  long long Qi = (long long)stats[(size_t)t * SSTR + 2 * c + 1];
#pragma unroll
  for (int off = 32; off; off >>= 1) {
    Si += __shfl_down(Si, off);
    Qi += __shfl_down(Qi, off);
  }
  if ((t & 63) == 0) { sS[t >> 6] = Si; sQ[t >> 6] = Qi; }
  __syncthreads();
  if (t != 0) return;
  const double S = (double)(sS[0] + sS[1] + sS[2] + sS[3]);
  const double Q = (double)(sQ[0] + sQ[1] + sQ[2] + sQ[3]);
  const double mu = S / Nel, var = Q / Nel - mu * mu;
  const double rr = 1.0 / sqrt(var + 1e-4);
  const double al = (double)g[c] * rr;
  const double bt = (double)be[c] - al * mu;
  int T, dir;
  if (al > 0.0) {
    dir = 1;
    const double tt = -bt / al;
    if (tt >= 6000.0) T = 6000;
    else if (tt <= -6000.0) T = -6000;
    else {
      T = (int)ceil(tt);
      if (fma(al, (double)(T - 1), bt) >= 0.0) T -= 1;
      else if (fma(al, (double)T, bt) < 0.0) T += 1;
    }
  } else if (al < 0.0) {
    dir = 0;
    const double tt = -bt / al;
    if (tt >= 6000.0) T = 6000;
    else if (tt <= -6000.0) T = -6000;
    else {
      T = (int)floor(tt);
      if (fma(al, (double)(T + 1), bt) >= 0.0) T += 1;
      else if (fma(al, (double)T, bt) < 0.0) T -= 1;
    }
  } else {
    dir = 1;
    T = (bt >= 0.0) ? -6000 : 6000;
  }
  thri[c] = make_int2(T, dir);
  (void)Co;
}

// ---- binarize (no pool): raw [np][CO] -> packed A [np][CO/32] ----
template <int P, int CO>
__global__ void __launch_bounds__(256) binz_r(const short* __restrict__ raw,
                                              const int2* __restrict__ thr,
                                              uint32_t* __restrict__ Aout) {
  constexpr int WDo = CO / 32;
  const int idx = blockIdx.x * 256 + threadIdx.x;
  if (idx >= 512 * P * WDo) return;
  const int np = idx / WDo, wd = idx % WDo;
  const short* p = raw + (size_t)np * CO + wd * 32;
  v4i q[4];
#pragma unroll
  for (int t = 0; t < 4; t++) q[t] = __builtin_nontemporal_load((const v4i*)p + t);
  const short* sv = (const short*)q;
  uint32_t word = 0;
#pragma unroll
  for (int j = 0; j < 32; j++) {
    const int v = sv[j];
    const int2 td = thr[wd * 32 + j];
    word |= (uint32_t)(td.y ? (v >= td.x) : (v <= td.x)) << j;
  }
  Aout[idx] = word;
}

// ---- pooled binarize from packed (min,max) planes [npo][CO] ----
template <int Po, int CO>
__global__ void __launch_bounds__(256) binpool_mm(const int* __restrict__ mm,
                                                  const int2* __restrict__ thr,
                                                  uint32_t* __restrict__ Aout) {
  constexpr int WDo = CO / 32;
  const int idx = blockIdx.x * 256 + threadIdx.x;
  if (idx >= 512 * Po * WDo) return;
  const int np = idx / WDo, wd = idx % WDo;
  const int* p = mm + (size_t)np * CO + wd * 32;
  v4i q[8];
#pragma unroll
  for (int t = 0; t < 8; t++) q[t] = __builtin_nontemporal_load((const v4i*)p + t);
  const int* iv = (const int*)q;
  uint32_t word = 0;
#pragma unroll
  for (int j = 0; j < 32; j++) {
    const int v = iv[j];
    const int mn = (short)(v & 0xFFFF), mx = (short)(v >> 16);
    const int2 td = thr[wd * 32 + j];
    const bool b = td.y ? (mx >= td.x) : (mn <= td.x);
    word |= (uint32_t)b << j;
  }
  Aout[idx] = word;
}

// ---- head: avgpool(4x4) + binary FC (exact in f32) ----
__global__ void __launch_bounds__(64) head_kern(const uint32_t* __restrict__ A6,
                                                const float* __restrict__ fcw,
                                                const float* __restrict__ fcb,
                                                float* __restrict__ fcout) {
  __shared__ uint32_t aw[128];
  __shared__ float feat[256];
  const int n = blockIdx.x, t = threadIdx.x;
  for (int i = t; i < 128; i += 64) aw[i] = A6[(size_t)n * 128 + i];
  __syncthreads();
#pragma unroll
  for (int k = 0; k < 4; k++) {
    const int c = t * 4 + k;
    const int wd = c >> 5, sh = c & 31;
    int cnt = 0;
#pragma unroll
    for (int pos = 0; pos < 16; pos++) cnt += (aw[pos * 8 + wd] >> sh) & 1;
    feat[c] = (float)(cnt - 8) * 0.125f;  // exact
  }
  __syncthreads();
  if (t < 10) {
    float acc = 0.f;  // all partial sums exactly representable
    for (int c = 0; c < 256; c++) acc += (fcw[t * 256 + c] >= 0.f ? feat[c] : -feat[c]);
    fcout[n * 10 + t] = acc + fcb[t];
  }
}

// ---- bn1d over batch: one block, wave per output channel ----
__global__ void __launch_bounds__(640) bn1d_kern(const float* __restrict__ fcout,
                                                 const float* __restrict__ g7,
                                                 const float* __restrict__ be7,
                                                 float* __restrict__ out) {
  const int t = threadIdx.x, o = t >> 6, lane = t & 63;
  double s = 0.0, q = 0.0;
  float v[8];
#pragma unroll
  for (int i = 0; i < 8; i++) {
    v[i] = fcout[(lane + 64 * i) * 10 + o];
    s += v[i];
    q += (double)v[i] * v[i];
  }
#pragma unroll
  for (int off = 32; off; off >>= 1) {
    s += __shfl_down(s, off);
    q += __shfl_down(q, off);
  }
  s = __shfl(s, 0);
  q = __shfl(q, 0);
  const double mu = s / 512.0, var = q / 512.0 - mu * mu;
  const double r = 1.0 / sqrt(var + 1e-5);
  const double al = (double)g7[o] * r;
  const double bt = (double)be7[o] - al * mu;
#pragma unroll
  for (int i = 0; i < 8; i++) out[(lane + 64 * i) * 10 + o] = (float)fma(al, (double)v[i], bt);
}

extern "C" void kernel_launch(void* const* d_in, const int* in_sizes, int n_in,
                              void* d_out, int out_size, void* d_ws, size_t ws_size,
                              hipStream_t stream) {
  const float* x = (const float*)d_in[0];
  const float* w1 = (const float*)d_in[1];
  const float* g1 = (const float*)d_in[3];
  const float* be1 = (const float*)d_in[4];
  const float* w2 = (const float*)d_in[5];
  const float* g2 = (const float*)d_in[7];
  const float* be2 = (const float*)d_in[8];
  const float* w3 = (const float*)d_in[9];
  const float* g3 = (const float*)d_in[11];
  const float* be3 = (const float*)d_in[12];
  const float* w4 = (const float*)d_in[13];
  const float* g4 = (const float*)d_in[15];
  const float* be4 = (const float*)d_in[16];
  const float* w5 = (const float*)d_in[17];
  const float* g5 = (const float*)d_in[19];
  const float* be5 = (const float*)d_in[20];
  const float* w6 = (const float*)d_in[21];
  const float* g6 = (const float*)d_in[23];
  const float* be6 = (const float*)d_in[24];
  const float* fcw = (const float*)d_in[25];
  const float* fcb = (const float*)d_in[26];
  const float* g7 = (const float*)d_in[27];
  const float* be7 = (const float*)d_in[28];
  float* out = (float*)d_out;

  char* ws = (char*)d_ws;
  size_t off = 0;
  auto take = [&](size_t bytes) -> char* {
    char* p = ws + off;
    off = (off + bytes + 255) & ~(size_t)255;
    return p;
  };
  uint32_t* A1 = (uint32_t*)take((size_t)512 * 1024 * 2 * 4);
  uint32_t* A2 = (uint32_t*)take((size_t)512 * 256 * 2 * 4);
  uint32_t* A3 = (uint32_t*)take((size_t)512 * 256 * 4 * 4);
  uint32_t* A4 = (uint32_t*)take((size_t)512 * 64 * 4 * 4);
  uint32_t* A5 = (uint32_t*)take((size_t)512 * 64 * 8 * 4);
  uint32_t* A6 = (uint32_t*)take((size_t)512 * 16 * 8 * 4);
  int8_t* w8 = (int8_t*)take((size_t)1142784);
  double2* part1 = (double2*)take((size_t)64 * 512 * 16);
  unsigned long long* stats = (unsigned long long*)take((size_t)NBKT * SSTR * 8);
  double2* thrD = (double2*)take((size_t)64 * 16);
  double* teD = (double*)take((size_t)64 * 8);
  int2* thri = (int2*)take((size_t)832 * 8);
  float* fcout = (float*)take((size_t)512 * 10 * 4);
  short* raw = (short*)take((size_t)64 * 512 * 1024 * 2);
  (void)ws_size; (void)in_sizes; (void)n_in; (void)out_size;

  pack8<<<4464, 256, 0, stream>>>(w2, w3, w4, w5, w6, w8, stats);

  conv1_p1<<<dim3(512, 4), 256, 0, stream>>>(x, w1, part1);
  conv1_fin<<<64, 256, 0, stream>>>(part1, g1, be1, w1, thrD, teD);
  // p2 writes planar staging (aliases raw: raw unused until L2 mconv)
  conv1_p2<<<dim3(512, 4), 256, 0, stream>>>(x, w1, thrD, teD, (uint16_t*)raw);
  a1merge<<<1024, 256, 0, stream>>>((const uint16_t*)raw, A1);

  // L2 (pool): 32x32, Ci=64, CO=64; SH=8 -> LDS 27KB, 4 strips, 2048 blocks
  mconv<32, 32, 8, 64, 64, 2, 4, 1><<<dim3(2048, 1), 256, 0, stream>>>(A1, w8, raw, stats + 0);
  bin_fin<<<64, 256, 0, stream>>>(stats + 0, g2, be2, thri + 0, 64, 512.0 * 1024.0);
  binpool_mm<256, 64><<<1024, 256, 0, stream>>>((const int*)raw, thri + 0, A2);

  // L3: 16x16, Ci=64, CO=128 (no pool)
  mconv<16, 16, 8, 64, 128, 4, 4, 0><<<dim3(1024, 1), 256, 0, stream>>>(A2, w8 + 36864, raw, stats + 128);
  bin_fin<<<128, 256, 0, stream>>>(stats + 128, g3, be3, thri + 64, 128, 512.0 * 256.0);
  binz_r<256, 128><<<2048, 256, 0, stream>>>(raw, thri + 64, A3);

  // L4 (pool): 16x16, Ci=128, CO=128 -> mm [npo][128]
  mconv<16, 16, 8, 128, 128, 4, 4, 1><<<dim3(1024, 1), 256, 0, stream>>>(A3, w8 + 110592, raw, stats + 384);
  bin_fin<<<128, 256, 0, stream>>>(stats + 384, g4, be4, thri + 192, 128, 512.0 * 256.0);
  binpool_mm<64, 128><<<512, 256, 0, stream>>>((const int*)raw, thri + 192, A4);

  // L5: 8x8, Ci=128, CO=256 (no pool)
  mconv<8, 8, 8, 128, 256, 4, 2, 0><<<dim3(512, 2), 256, 0, stream>>>(A4, w8 + 258048, raw, stats + 640);
  bin_fin<<<256, 256, 0, stream>>>(stats + 640, g5, be5, thri + 320, 256, 512.0 * 64.0);
  binz_r<64, 256><<<1024, 256, 0, stream>>>(raw, thri + 320, A5);

  // L6 (pool): 8x8, Ci=256, CO=256 -> mm [npo][256]
  mconv<8, 8, 8, 256, 256, 4, 2, 1><<<dim3(512, 2), 256, 0, stream>>>(A5, w8 + 552960, raw, stats + 1152);
  bin_fin<<<256, 256, 0, stream>>>(stats + 1152, g6, be6, thri + 576, 256, 512.0 * 64.0);
  binpool_mm<16, 256><<<256, 256, 0, stream>>>((const int*)raw, thri + 576, A6);

  head_kern<<<512, 64, 0, stream>>>(A6, fcw, fcb, fcout);
  bn1d_kern<<<1, 640, 0, stream>>>(fcout, g7, be7, out);
}

// Round 26
// 336.930 us; speedup vs baseline: 1.0203x; 1.0033x over previous
//
#include <hip/hip_runtime.h>
#include <cstdint>

// ---------------------------------------------------------------------------
// BinaryNet forward, MFMA edition.  (Session-best verified configuration.)
//  * binary_tanh(bn2d(conv+b)) == threshold on exact integer conv value.
//  * binary conv == i8 GEMM via mfma_i32_32x32x32_i8 -> exact integers.
//  * integer thresholds T (verified with f64 fma) -> binarize bit-identical.
//  * stats: 256-bucket privatized atomics + parallel bucket reduction.
//  * pool layers: in-register 2x2 (min,max) packed int32.
//  * Config ledger (all alternatives measured and reverted):
//    - conv1_p1: (256,6), VGPR 40, ~60us.  (256,8)->VGPR32 re-read;
//      wpe(2,2)->occ 20%; all ~60-68us.  Latency-bound floor.
//    - conv1_p2: wpe(2,2) ONLY.  (256,4)/wpe(3,4) spill (45-135MB scratch).
//    - mconv: (256,4) + CHK=(MG==4?1:2) (round-23 win, -13us);
//      L2 SH=8 lifts LDS cap 3->4 blocks/CU (round-24 win).
//    - stats atomics: 256-bucket privatization (round-11 win, -100us).
// ---------------------------------------------------------------------------

typedef int v4i __attribute__((ext_vector_type(4)));
typedef int v16i __attribute__((ext_vector_type(16)));

#define NBKT 256       // stats buckets
#define SSTR 1664      // stats words per bucket (2*832)

// ---- weight pack: sign(+-1) i8 + stats zeroing -----------------------------
__global__ void __launch_bounds__(256) pack8(const float* __restrict__ w2,
                                             const float* __restrict__ w3,
                                             const float* __restrict__ w4,
                                             const float* __restrict__ w5,
                                             const float* __restrict__ w6,
                                             int8_t* __restrict__ w8,
                                             unsigned long long* __restrict__ stats) {
  const int idx = blockIdx.x * 256 + threadIdx.x;
  if (idx < NBKT * SSTR) stats[idx] = 0ull;
  const float* w; int CiL, e; int8_t* dst;
  if (idx < 36864)        { w = w2; CiL = 64;  e = idx;          dst = w8; }
  else if (idx < 110592)  { w = w3; CiL = 64;  e = idx - 36864;  dst = w8 + 36864; }
  else if (idx < 258048)  { w = w4; CiL = 128; e = idx - 110592; dst = w8 + 110592; }
  else if (idx < 552960)  { w = w5; CiL = 128; e = idx - 258048; dst = w8 + 258048; }
  else if (idx < 1142784) { w = w6; CiL = 256; e = idx - 552960; dst = w8 + 552960; }
  else return;
  const int WDk = CiL / 32;
  const int b = e & 15;
  const int l31 = (e >> 4) & 31;
  const int hi = (e >> 9) & 1;
  const int kc = (e >> 10) % WDk;
  const int tap = (e / (1024 * WDk)) % 9;
  const int cb = e / (9216 * WDk);
  const int co = cb * 32 + l31;
  const int ci = kc * 32 + hi * 16 + b;
  dst[e] = (w[((size_t)co * CiL + ci) * 9 + tap] >= 0.f) ? (int8_t)1 : (int8_t)-1;
}

// ---- conv1 pass 1: f32 conv, 2 channels per window pass, f64 stats ---------
__global__ void __launch_bounds__(256, 6) conv1_p1(const float* __restrict__ x,
                                                   const float* __restrict__ w1,
                                                   double2* __restrict__ part) {
  __shared__ float ximg[3][34][34];
  __shared__ float wl[16][28];
  __shared__ double pS[16][4], pQ[16][4];
  const int tid = threadIdx.x, n = blockIdx.x, cg = blockIdx.y;
  for (int i = tid; i < 3 * 34 * 34; i += 256) ((float*)ximg)[i] = 0.f;
  for (int i = tid; i < 16 * 27; i += 256) wl[i / 27][i % 27] = w1[cg * 432 + i];
  __syncthreads();
  const float* xb = x + (size_t)n * 3072;
  for (int i = tid; i < 3072; i += 256) {
    const int c = i >> 10, p = i & 1023;
    ximg[c][(p >> 5) + 1][(p & 31) + 1] = xb[i];
  }
  __syncthreads();
  const int h = tid >> 3, w0 = (tid & 7) * 4;
  const int lane = tid & 63, wv = tid >> 6;
  for (int c = 0; c < 16; c += 2) {
    float4 wa4[7], wb4[7];
#pragma unroll
    for (int i = 0; i < 7; i++) {
      wa4[i] = *(const float4*)&wl[c][i * 4];
      wb4[i] = *(const float4*)&wl[c + 1][i * 4];
    }
    const float* wfa = (const float*)wa4;
    const float* wfb = (const float*)wb4;
    float accA[4] = {0.f, 0.f, 0.f, 0.f};
    float accB[4] = {0.f, 0.f, 0.f, 0.f};
#pragma unroll
    for (int ic = 0; ic < 3; ic++)
#pragma unroll
      for (int ky = 0; ky < 3; ky++) {
        float xr[6];
#pragma unroll
        for (int t = 0; t < 6; t++) xr[t] = ximg[ic][h + ky][w0 + t];
#pragma unroll
        for (int kx = 0; kx < 3; kx++) {
          const float wga = wfa[ic * 9 + ky * 3 + kx];
          const float wgb = wfb[ic * 9 + ky * 3 + kx];
#pragma unroll
          for (int j = 0; j < 4; j++) {
            accA[j] = fmaf(xr[j + kx], wga, accA[j]);
            accB[j] = fmaf(xr[j + kx], wgb, accB[j]);
          }
        }
      }
    // stats, same per-channel f64 order as always
    double s = (double)accA[0] + accA[1] + accA[2] + accA[3];
    double q = (double)accA[0] * accA[0] + (double)accA[1] * accA[1] +
               (double)accA[2] * accA[2] + (double)accA[3] * accA[3];
    double s2 = (double)accB[0] + accB[1] + accB[2] + accB[3];
    double q2 = (double)accB[0] * accB[0] + (double)accB[1] * accB[1] +
                (double)accB[2] * accB[2] + (double)accB[3] * accB[3];
#pragma unroll
    for (int off = 32; off; off >>= 1) {
      s += __shfl_down(s, off);
      q += __shfl_down(q, off);
      s2 += __shfl_down(s2, off);
      q2 += __shfl_down(q2, off);
    }
    if (lane == 0) {
      pS[c][wv] = s;      pQ[c][wv] = q;
      pS[c + 1][wv] = s2; pQ[c + 1][wv] = q2;
    }
  }
  __syncthreads();
  if (tid < 16) {
    const double S = pS[tid][0] + pS[tid][1] + pS[tid][2] + pS[tid][3];
    const double Q = pQ[tid][0] + pQ[tid][1] + pQ[tid][2] + pQ[tid][3];
    part[(size_t)(cg * 16 + tid) * 512 + n] = make_double2(S, Q);
  }
}

// ---- conv1_fin: parallel tree reduction over the 512 per-image partials ----
__global__ void __launch_bounds__(256) conv1_fin(const double2* __restrict__ part,
                                                 const float* __restrict__ g,
                                                 const float* __restrict__ be,
                                                 const float* __restrict__ w1,
                                                 double2* __restrict__ thr,
                                                 double* __restrict__ te) {
  __shared__ double sS[4], sQ[4];
  const int c = blockIdx.x;  // 64 blocks
  const int t = threadIdx.x;
  const double2 a = part[(size_t)c * 512 + t];
  const double2 b = part[(size_t)c * 512 + 256 + t];
  double S = a.x + b.x, Q = a.y + b.y;
#pragma unroll
  for (int off = 32; off; off >>= 1) {
    S += __shfl_down(S, off);
    Q += __shfl_down(Q, off);
  }
  if ((t & 63) == 0) { sS[t >> 6] = S; sQ[t >> 6] = Q; }
  __syncthreads();
  if (t != 0) return;
  S = sS[0] + sS[1] + sS[2] + sS[3];
  Q = sQ[0] + sQ[1] + sQ[2] + sQ[3];
  const double Nel = 512.0 * 1024.0;
  const double mu = S / Nel, var = Q / Nel - mu * mu;
  const double r = 1.0 / sqrt(var + 1e-4);
  const double al = (double)g[c] * r;
  const double bt = (double)be[c] - al * mu;
  thr[c] = make_double2(al, bt);
  double ws = 0.0;
  for (int k = 0; k < 27; k++) ws += fabs((double)w1[c * 27 + k]);
  te[c] = fabs(al) * 27.0 * 5.9604644775390625e-08 * ws * 1.25;
}

// ---- conv1 pass 2: f32 conv + f32 certified bounds + exact-f64 fallback ----
__global__ void __launch_bounds__(256)
__attribute__((amdgpu_waves_per_eu(2, 2)))
conv1_p2(const float* __restrict__ x, const float* __restrict__ w1,
         const double2* __restrict__ thr, const double* __restrict__ te,
         uint16_t* __restrict__ stg) {
  __shared__ float ximg[3][34][34];
  __shared__ float wl[16][28];
  __shared__ float bndLo[16], bndHi[16];
  __shared__ uint32_t bflag[16];   // bit0 = decision when v>=hi, bit1 = when v<=lo
  __shared__ float smx[4];
  const int tid = threadIdx.x, n = blockIdx.x, cg = blockIdx.y;
  for (int i = tid; i < 3 * 34 * 34; i += 256) ((float*)ximg)[i] = 0.f;
  for (int i = tid; i < 16 * 27; i += 256) wl[i / 27][i % 27] = w1[cg * 432 + i];
  __syncthreads();
  const float* xb = x + (size_t)n * 3072;
  float mx = 0.f;
  for (int i = tid; i < 3072; i += 256) {
    const int c = i >> 10, p = i & 1023;
    const float v = xb[i];
    ximg[c][(p >> 5) + 1][(p & 31) + 1] = v;
    mx = fmaxf(mx, fabsf(v));
  }
  const int lane = tid & 63, wv = tid >> 6;
#pragma unroll
  for (int off = 32; off; off >>= 1) mx = fmaxf(mx, __shfl_xor(mx, off));
  if (lane == 0) smx[wv] = mx;
  __syncthreads();
  const double Xmax = (double)fmaxf(fmaxf(smx[0], smx[1]), fmaxf(smx[2], smx[3]));
  if (tid < 16) {
    const double2 ab = thr[cg * 16 + tid];
    const double ef = te[cg * 16 + tid] * Xmax;
    float lf, hf;
    uint32_t fl;
    if (ab.x > 0.0 || ab.x < 0.0) {
      const double e1 = (ef - ab.y) / ab.x;
      const double e2 = (-ef - ab.y) / ab.x;
      const double bLo = fmin(e1, e2), bHi = fmax(e1, e2);
      hf = (float)(bHi + fabs(bHi) * 1e-6 + 1e-25);
      lf = (float)(bLo - fabs(bLo) * 1e-6 - 1e-25);
      const uint32_t dhi = (ab.x > 0.0) ? 1u : 0u;
      fl = dhi | ((1u - dhi) << 1);   // dlo = !dhi
    } else {
      hf = -3.4e38f;
      lf = -3.4e38f;
      fl = (ab.y >= 0.0) ? 1u : 0u;
    }
    bndLo[tid] = lf;
    bndHi[tid] = hf;
    bflag[tid] = fl;
  }
  __syncthreads();
  const int h = tid >> 3, w0 = (tid & 7) * 4;
  float win[3][3][6];
#pragma unroll
  for (int ic = 0; ic < 3; ic++)
#pragma unroll
    for (int ky = 0; ky < 3; ky++)
#pragma unroll
      for (int t = 0; t < 6; t++) win[ic][ky][t] = ximg[ic][h + ky][w0 + t];
  uint32_t wbits[4] = {0u, 0u, 0u, 0u};
  for (int c = 0; c < 16; c++) {
    float4 wv4[7];
#pragma unroll
    for (int i = 0; i < 7; i++) wv4[i] = *(const float4*)&wl[c][i * 4];
    const float* wf = (const float*)wv4;
    float acc[4] = {0.f, 0.f, 0.f, 0.f};
#pragma unroll
    for (int ic = 0; ic < 3; ic++)
#pragma unroll
      for (int ky = 0; ky < 3; ky++)
#pragma unroll
        for (int kx = 0; kx < 3; kx++) {
          const float wgt = wf[ic * 9 + ky * 3 + kx];
#pragma unroll
          for (int j = 0; j < 4; j++) acc[j] = fmaf(win[ic][ky][j + kx], wgt, acc[j]);
        }
    const float lf = bndLo[c], hf = bndHi[c];
    const uint32_t fl = bflag[c];
#pragma unroll
    for (int j = 0; j < 4; j++) {
      const float v = acc[j];
      uint32_t bit;
      if (v >= hf) {
        bit = fl & 1u;
      } else if (v <= lf) {
        bit = (fl >> 1) & 1u;
      } else {
        // rare: re-derive exactly (same fma order as the all-f64 chain)
        double a64 = 0.0;
        for (int k = 0; k < 27; k++) {
          const int ic = k / 9, rr = k % 9, ky = rr / 3, kx = rr % 3;
          a64 = fma((double)ximg[ic][h + ky][w0 + j + kx], (double)wl[c][k], a64);
        }
        const double2 ab = thr[cg * 16 + c];
        bit = (fma(ab.x, a64, ab.y) >= 0.0) ? 1u : 0u;
      }
      if (bit) wbits[j] |= 1u << c;
    }
  }
  // packed 8B store, planar [cg][np]: coalesced (consecutive lanes -> 8B apart)
  const int p0 = h * 32 + w0;
  uint2 pkd;
  pkd.x = (wbits[0] & 0xFFFFu) | (wbits[1] << 16);
  pkd.y = (wbits[2] & 0xFFFFu) | (wbits[3] << 16);
  *(uint2*)&stg[(size_t)cg * 524288 + (size_t)n * 1024 + p0] = pkd;
}

// ---- zip 4 staging planes into A1 [np][2] words (c = wd*32 + half*16 + j) --
__global__ void __launch_bounds__(256) a1merge(const uint16_t* __restrict__ stg,
                                               uint32_t* __restrict__ A1) {
  const int idx = blockIdx.x * 256 + threadIdx.x;  // 2 np per thread
  const int np = idx * 2;
  if (np >= 512 * 1024) return;
  const uint32_t a0 = *(const uint32_t*)&stg[0 * 524288 + np];
  const uint32_t a1 = *(const uint32_t*)&stg[1 * 524288 + np];
  const uint32_t a2 = *(const uint32_t*)&stg[2 * 524288 + np];
  const uint32_t a3 = *(const uint32_t*)&stg[3 * 524288 + np];
  uint4 o;
  o.x = (a0 & 0xFFFFu) | (a1 << 16);
  o.y = (a2 & 0xFFFFu) | (a3 << 16);
  o.z = (a0 >> 16) | (a1 & 0xFFFF0000u);
  o.w = (a2 >> 16) | (a3 & 0xFFFF0000u);
  *(uint4*)&A1[(size_t)np * 2] = o;
}

// ---- MFMA binary conv v6: CHK tuned per-layer, 4 waves/EU ------------------
template <int H, int W, int SH, int Ci, int CO, int WN, int MG, int POOL>
__global__ void __launch_bounds__(256, 4)
mconv(const uint32_t* __restrict__ Ain, const int8_t* __restrict__ w8,
      short* __restrict__ raw, unsigned long long* __restrict__ stats) {
  constexpr int WD = Ci / 32, Wp = W + 2, Cs = Ci + 16, P = H * W;
  constexpr int STRIPS = H / SH;
  constexpr int MT = SH * W / 32;
  constexpr int WM = 4 / WN;
  constexpr int MTW = MT / WM;
  constexpr int NG = MTW / MG;
  constexpr int CHK = (MG == 4) ? 1 : 2;   // bound live set: bf + acc <= ~120
  constexpr int NCH = WD / CHK;
  constexpr int IMGB = (SH + 2) * Wp * Cs;
  constexpr int Wo = W / 2, Po = (H / 2) * Wo;
  static_assert(NG >= 1 && MTW == NG * MG && WD % CHK == 0, "bad geometry");
  __shared__ __align__(16) uint32_t img[IMGB / 4];
  const int tid = threadIdx.x;
  const int n = blockIdx.x / STRIPS, s = blockIdx.x % STRIPS;
  int* __restrict__ mm = (int*)raw;

  for (int i = tid; i < IMGB / 4; i += 256) img[i] = 0u;
  __syncthreads();
  constexpr int ROWW = W * WD;
  for (int i = tid; i < (SH + 2) * ROWW; i += 256) {
    const int lr = i / ROWW;
    const int h = s * SH - 1 + lr;
    if (h < 0 || h >= H) continue;
    const int rem = i % ROWW;
    const int wpx = rem / WD, d = rem % WD;
    const uint32_t bits = Ain[((size_t)n * P + h * W + wpx) * WD + d];
    uint32_t* dst = img + ((lr * Wp + wpx + 1) * Cs) / 4 + d * 8;
#pragma unroll
    for (int nb2 = 0; nb2 < 8; nb2++) {
      const uint32_t t = (((bits >> (4 * nb2)) & 0xFu) * 0x00204081u) & 0x01010101u;
      dst[nb2] = 0x01010101u + (t ^ 0x01010101u) * 0xFEu;
    }
  }
  __syncthreads();

  const int wv = tid >> 6, lane = tid & 63, l31 = lane & 31, hi = lane >> 5;
  const int nb = wv % WN, ms = wv / WN;
  const int cb = blockIdx.y * WN + nb;
  const int co = cb * 32 + l31;
  const int8_t* wbl = w8 + (size_t)cb * 9 * WD * 1024 + (size_t)lane * 16;
  const char* imgb = (const char*)img;
  int sA = 0, qA = 0;
#pragma unroll 1
  for (int mg = 0; mg < NG; mg++) {
    v16i acc[MG];
#pragma unroll
    for (int m = 0; m < MG; m++)
      acc[m] = (v16i){0, 0, 0, 0, 0, 0, 0, 0, 0, 0, 0, 0, 0, 0, 0, 0};
    int ab[MG];
#pragma unroll
    for (int m = 0; m < MG; m++) {
      const int mt = ms * MTW + mg * MG + m;
      const int pp = mt * 32 + l31;
      ab[m] = ((pp / W) * Wp + (pp % W)) * Cs + hi * 16;
    }
#pragma unroll 1
    for (int ch = 0; ch < NCH; ++ch) {
      v4i bf[9 * CHK];
#pragma unroll
      for (int t9 = 0; t9 < 9; t9++)
#pragma unroll
        for (int c = 0; c < CHK; c++)
          bf[t9 * CHK + c] =
              *(const v4i*)(wbl + (size_t)(t9 * WD + ch * CHK + c) * 1024);
#pragma unroll
      for (int tap = 0; tap < 9; tap++) {
        const int toff = ((tap / 3) * Wp + (tap % 3)) * Cs;
#pragma unroll
        for (int c = 0; c < CHK; c++)
#pragma unroll
          for (int m = 0; m < MG; m++) {
            const v4i a =
                *(const v4i*)(imgb + ab[m] + toff + (ch * CHK + c) * 32);
            acc[m] = __builtin_amdgcn_mfma_i32_32x32x32_i8(a, bf[tap * CHK + c],
                                                           acc[m], 0, 0, 0);
          }
      }
    }
#pragma unroll
    for (int m = 0; m < MG; m++)
#pragma unroll
      for (int r = 0; r < 16; r++) {
        const int v = acc[m][r];
        sA += v;
        qA += v * v;
      }
    if constexpr (POOL) {
      if constexpr (W == 32) {
#pragma unroll
        for (int mp = 0; mp < MG / 2; mp++) {
          const int mt0 = ms * MTW + mg * MG + 2 * mp;
          const int ho = (s * SH + mt0) >> 1;
#pragma unroll
          for (int r = 0; r < 16; r += 2) {
            const int v00 = acc[2 * mp][r], v01 = acc[2 * mp][r + 1];
            const int v10 = acc[2 * mp + 1][r], v11 = acc[2 * mp + 1][r + 1];
            const int mn = min(min(v00, v01), min(v10, v11));
            const int mxv = max(max(v00, v01), max(v10, v11));
            const int wo = ((r & 3) + 8 * (r >> 2) + 4 * hi) >> 1;
            mm[((size_t)n * Po + ho * Wo + wo) * CO + co] =
                (int)(((uint32_t)(uint16_t)(short)mxv << 16) |
                      (uint32_t)(uint16_t)(short)mn);
          }
        }
      } else if constexpr (W == 16) {
#pragma unroll
        for (int m = 0; m < MG; m++) {
          const int mt = ms * MTW + mg * MG + m;
          const int ho = (s * SH) / 2 + mt;
#pragma unroll
          for (int r = 0; r < 8; r += 2) {
            const int v00 = acc[m][r], v01 = acc[m][r + 1];
            const int v10 = acc[m][r + 8], v11 = acc[m][r + 9];
            const int mn = min(min(v00, v01), min(v10, v11));
            const int mxv = max(max(v00, v01), max(v10, v11));
            const int wo = ((r & 3) + 8 * (r >> 2) + 4 * hi) >> 1;
            mm[((size_t)n * Po + ho * Wo + wo) * CO + co] =
                (int)(((uint32_t)(uint16_t)(short)mxv << 16) |
                      (uint32_t)(uint16_t)(short)mn);
          }
        }
      } else {
#pragma unroll
        for (int m = 0; m < MG; m++) {
          const int mt = ms * MTW + mg * MG + m;
#pragma unroll
          for (int rb = 0; rb < 2; rb++)
#pragma unroll
            for (int rr = 0; rr < 4; rr += 2) {
              const int r = rb * 8 + rr;
              const int v00 = acc[m][r], v01 = acc[m][r + 1];
              const int v10 = acc[m][r + 4], v11 = acc[m][r + 5];
              const int mn = min(min(v00, v01), min(v10, v11));
              const int mxv = max(max(v00, v01), max(v10, v11));
              const int ho = (s * SH) / 2 + 2 * mt + rb;
              const int wo = (rr + 4 * hi) >> 1;
              mm[((size_t)n * Po + ho * Wo + wo) * CO + co] =
                  (int)(((uint32_t)(uint16_t)(short)mxv << 16) |
                        (uint32_t)(uint16_t)(short)mn);
            }
        }
      }
    } else {
#pragma unroll
      for (int m = 0; m < MG; m++) {
        const int mt = ms * MTW + mg * MG + m;
#pragma unroll
        for (int r = 0; r < 16; r++) {
          const int row = (r & 3) + 8 * (r >> 2) + 4 * hi;
          const int p = s * SH * W + mt * 32 + row;
          raw[((size_t)n * P + p) * CO + co] = (short)acc[m][r];
        }
      }
    }
  }
  sA += __shfl_xor(sA, 32);
  qA += __shfl_xor(qA, 32);
  if (hi == 0) {
    const size_t bkt = (size_t)(blockIdx.x & (NBKT - 1)) * SSTR;
    atomicAdd(&stats[bkt + 2 * co], (unsigned long long)(long long)sA);
    atomicAdd(&stats[bkt + 2 * co + 1], (unsigned long long)(long long)qA);
  }
}

// ---- BN threshold: PARALLEL bucket reduction (exact integer sums) ----------
__global__ void __launch_bounds__(256) bin_fin(const unsigned long long* __restrict__ stats,
                                               const float* __restrict__ g,
                                               const float* __restrict__ be,
                                               int2* __restrict__ thri, int Co,
                                               double Nel) {
  __shared__ long long sS[4], sQ[4];
  const int c = blockIdx.x;
  const int t = threadIdx.x;
  long long Si = (long long)stats[(size_t)t * SSTR + 2 * c];
  long long Qi = (long long)stats[(size_t)t * SSTR + 2 * c + 1];
#pragma unroll
  for (int off = 32; off; off >>= 1) {
    Si += __shfl_down(Si, off);
    Qi += __shfl_down(Qi, off);
  }
  if ((t & 63) == 0) { sS[t >> 6] = Si; sQ[t >> 6] = Qi; }
  __syncthreads();
  if (t != 0) return;
  const double S = (double)(sS[0] + sS[1] + sS[2] + sS[3]);
  const double Q = (double)(sQ[0] + sQ[1] + sQ[2] + sQ[3]);
  const double mu = S / Nel, var = Q / Nel - mu * mu;
  const double rr = 1.0 / sqrt(var + 1e-4);
  const double al = (double)g[c] * rr;
  const double bt = (double)be[c] - al * mu;
  int T, dir;
  if (al > 0.0) {
    dir = 1;
    const double tt = -bt / al;
    if (tt >= 6000.0) T = 6000;
    else if (tt <= -6000.0) T = -6000;
    else {
      T = (int)ceil(tt);
      if (fma(al, (double)(T - 1), bt) >= 0.0) T -= 1;
      else if (fma(al, (double)T, bt) < 0.0) T += 1;
    }
  } else if (al < 0.0) {
    dir = 0;
    const double tt = -bt / al;
    if (tt >= 6000.0) T = 6000;
    else if (tt <= -6000.0) T = -6000;
    else {
      T = (int)floor(tt);
      if (fma(al, (double)(T + 1), bt) >= 0.0) T += 1;
      else if (fma(al, (double)T, bt) < 0.0) T -= 1;
    }
  } else {
    dir = 1;
    T = (bt >= 0.0) ? -6000 : 6000;
  }
  thri[c] = make_int2(T, dir);
  (void)Co;
}

// ---- binarize (no pool): raw [np][CO] -> packed A [np][CO/32] ----
template <int P, int CO>
__global__ void __launch_bounds__(256) binz_r(const short* __restrict__ raw,
                                              const int2* __restrict__ thr,
                                              uint32_t* __restrict__ Aout) {
  constexpr int WDo = CO / 32;
  const int idx = blockIdx.x * 256 + threadIdx.x;
  if (idx >= 512 * P * WDo) return;
  const int np = idx / WDo, wd = idx % WDo;
  const short* p = raw + (size_t)np * CO + wd * 32;
  v4i q[4];
#pragma unroll
  for (int t = 0; t < 4; t++) q[t] = __builtin_nontemporal_load((const v4i*)p + t);
  const short* sv = (const short*)q;
  uint32_t word = 0;
#pragma unroll
  for (int j = 0; j < 32; j++) {
    const int v = sv[j];
    const int2 td = thr[wd * 32 + j];
    word |= (uint32_t)(td.y ? (v >= td.x) : (v <= td.x)) << j;
  }
  Aout[idx] = word;
}

// ---- pooled binarize from packed (min,max) planes [npo][CO] ----
template <int Po, int CO>
__global__ void __launch_bounds__(256) binpool_mm(const int* __restrict__ mm,
                                                  const int2* __restrict__ thr,
                                                  uint32_t* __restrict__ Aout) {
  constexpr int WDo = CO / 32;
  const int idx = blockIdx.x * 256 + threadIdx.x;
  if (idx >= 512 * Po * WDo) return;
  const int np = idx / WDo, wd = idx % WDo;
  const int* p = mm + (size_t)np * CO + wd * 32;
  v4i q[8];
#pragma unroll
  for (int t = 0; t < 8; t++) q[t] = __builtin_nontemporal_load((const v4i*)p + t);
  const int* iv = (const int*)q;
  uint32_t word = 0;
#pragma unroll
  for (int j = 0; j < 32; j++) {
    const int v = iv[j];
    const int mn = (short)(v & 0xFFFF), mx = (short)(v >> 16);
    const int2 td = thr[wd * 32 + j];
    const bool b = td.y ? (mx >= td.x) : (mn <= td.x);
    word |= (uint32_t)b << j;
  }
  Aout[idx] = word;
}

// ---- head: avgpool(4x4) + binary FC (exact in f32) ----
__global__ void __launch_bounds__(64) head_kern(const uint32_t* __restrict__ A6,
                                                const float* __restrict__ fcw,
                                                const float* __restrict__ fcb,
                                                float* __restrict__ fcout) {
  __shared__ uint32_t aw[128];
  __shared__ float feat[256];
  const int n = blockIdx.x, t = threadIdx.x;
  for (int i = t; i < 128; i += 64) aw[i] = A6[(size_t)n * 128 + i];
  __syncthreads();
#pragma unroll
  for (int k = 0; k < 4; k++) {
    const int c = t * 4 + k;
    const int wd = c >> 5, sh = c & 31;
    int cnt = 0;
#pragma unroll
    for (int pos = 0; pos < 16; pos++) cnt += (aw[pos * 8 + wd] >> sh) & 1;
    feat[c] = (float)(cnt - 8) * 0.125f;  // exact
  }
  __syncthreads();
  if (t < 10) {
    float acc = 0.f;  // all partial sums exactly representable
    for (int c = 0; c < 256; c++) acc += (fcw[t * 256 + c] >= 0.f ? feat[c] : -feat[c]);
    fcout[n * 10 + t] = acc + fcb[t];
  }
}

// ---- bn1d over batch: one block, wave per output channel ----
__global__ void __launch_bounds__(640) bn1d_kern(const float* __restrict__ fcout,
                                                 const float* __restrict__ g7,
                                                 const float* __restrict__ be7,
                                                 float* __restrict__ out) {
  const int t = threadIdx.x, o = t >> 6, lane = t & 63;
  double s = 0.0, q = 0.0;
  float v[8];
#pragma unroll
  for (int i = 0; i < 8; i++) {
    v[i] = fcout[(lane + 64 * i) * 10 + o];
    s += v[i];
    q += (double)v[i] * v[i];
  }
#pragma unroll
  for (int off = 32; off; off >>= 1) {
    s += __shfl_down(s, off);
    q += __shfl_down(q, off);
  }
  s = __shfl(s, 0);
  q = __shfl(q, 0);
  const double mu = s / 512.0, var = q / 512.0 - mu * mu;
  const double r = 1.0 / sqrt(var + 1e-5);
  const double al = (double)g7[o] * r;
  const double bt = (double)be7[o] - al * mu;
#pragma unroll
  for (int i = 0; i < 8; i++) out[(lane + 64 * i) * 10 + o] = (float)fma(al, (double)v[i], bt);
}

extern "C" void kernel_launch(void* const* d_in, const int* in_sizes, int n_in,
                              void* d_out, int out_size, void* d_ws, size_t ws_size,
                              hipStream_t stream) {
  const float* x = (const float*)d_in[0];
  const float* w1 = (const float*)d_in[1];
  const float* g1 = (const float*)d_in[3];
  const float* be1 = (const float*)d_in[4];
  const float* w2 = (const float*)d_in[5];
  const float* g2 = (const float*)d_in[7];
  const float* be2 = (const float*)d_in[8];
  const float* w3 = (const float*)d_in[9];
  const float* g3 = (const float*)d_in[11];
  const float* be3 = (const float*)d_in[12];
  const float* w4 = (const float*)d_in[13];
  const float* g4 = (const float*)d_in[15];
  const float* be4 = (const float*)d_in[16];
  const float* w5 = (const float*)d_in[17];
  const float* g5 = (const float*)d_in[19];
  const float* be5 = (const float*)d_in[20];
  const float* w6 = (const float*)d_in[21];
  const float* g6 = (const float*)d_in[23];
  const float* be6 = (const float*)d_in[24];
  const float* fcw = (const float*)d_in[25];
  const float* fcb = (const float*)d_in[26];
  const float* g7 = (const float*)d_in[27];
  const float* be7 = (const float*)d_in[28];
  float* out = (float*)d_out;

  char* ws = (char*)d_ws;
  size_t off = 0;
  auto take = [&](size_t bytes) -> char* {
    char* p = ws + off;
    off = (off + bytes + 255) & ~(size_t)255;
    return p;
  };
  uint32_t* A1 = (uint32_t*)take((size_t)512 * 1024 * 2 * 4);
  uint32_t* A2 = (uint32_t*)take((size_t)512 * 256 * 2 * 4);
  uint32_t* A3 = (uint32_t*)take((size_t)512 * 256 * 4 * 4);
  uint32_t* A4 = (uint32_t*)take((size_t)512 * 64 * 4 * 4);
  uint32_t* A5 = (uint32_t*)take((size_t)512 * 64 * 8 * 4);
  uint32_t* A6 = (uint32_t*)take((size_t)512 * 16 * 8 * 4);
  int8_t* w8 = (int8_t*)take((size_t)1142784);
  double2* part1 = (double2*)take((size_t)64 * 512 * 16);
  unsigned long long* stats = (unsigned long long*)take((size_t)NBKT * SSTR * 8);
  double2* thrD = (double2*)take((size_t)64 * 16);
  double* teD = (double*)take((size_t)64 * 8);
  int2* thri = (int2*)take((size_t)832 * 8);
  float* fcout = (float*)take((size_t)512 * 10 * 4);
  short* raw = (short*)take((size_t)64 * 512 * 1024 * 2);
  (void)ws_size; (void)in_sizes; (void)n_in; (void)out_size;

  pack8<<<4464, 256, 0, stream>>>(w2, w3, w4, w5, w6, w8, stats);

  conv1_p1<<<dim3(512, 4), 256, 0, stream>>>(x, w1, part1);
  conv1_fin<<<64, 256, 0, stream>>>(part1, g1, be1, w1, thrD, teD);
  // p2 writes planar staging (aliases raw: raw unused until L2 mconv)
  conv1_p2<<<dim3(512, 4), 256, 0, stream>>>(x, w1, thrD, teD, (uint16_t*)raw);
  a1merge<<<1024, 256, 0, stream>>>((const uint16_t*)raw, A1);

  // L2 (pool): 32x32, Ci=64, CO=64; SH=8 -> LDS 27KB, 4 strips, 2048 blocks
  mconv<32, 32, 8, 64, 64, 2, 4, 1><<<dim3(2048, 1), 256, 0, stream>>>(A1, w8, raw, stats + 0);
  bin_fin<<<64, 256, 0, stream>>>(stats + 0, g2, be2, thri + 0, 64, 512.0 * 1024.0);
  binpool_mm<256, 64><<<1024, 256, 0, stream>>>((const int*)raw, thri + 0, A2);

  // L3: 16x16, Ci=64, CO=128 (no pool)
  mconv<16, 16, 8, 64, 128, 4, 4, 0><<<dim3(1024, 1), 256, 0, stream>>>(A2, w8 + 36864, raw, stats + 128);
  bin_fin<<<128, 256, 0, stream>>>(stats + 128, g3, be3, thri + 64, 128, 512.0 * 256.0);
  binz_r<256, 128><<<2048, 256, 0, stream>>>(raw, thri + 64, A3);

  // L4 (pool): 16x16, Ci=128, CO=128 -> mm [npo][128]
  mconv<16, 16, 8, 128, 128, 4, 4, 1><<<dim3(1024, 1), 256, 0, stream>>>(A3, w8 + 110592, raw, stats + 384);
  bin_fin<<<128, 256, 0, stream>>>(stats + 384, g4, be4, thri + 192, 128, 512.0 * 256.0);
  binpool_mm<64, 128><<<512, 256, 0, stream>>>((const int*)raw, thri + 192, A4);

  // L5: 8x8, Ci=128, CO=256 (no pool)
  mconv<8, 8, 8, 128, 256, 4, 2, 0><<<dim3(512, 2), 256, 0, stream>>>(A4, w8 + 258048, raw, stats + 640);
  bin_fin<<<256, 256, 0, stream>>>(stats + 640, g5, be5, thri + 320, 256, 512.0 * 64.0);
  binz_r<64, 256><<<1024, 256, 0, stream>>>(raw, thri + 320, A5);

  // L6 (pool): 8x8, Ci=256, CO=256 -> mm [npo][256]
  mconv<8, 8, 8, 256, 256, 4, 2, 1><<<dim3(512, 2), 256, 0, stream>>>(A5, w8 + 552960, raw, stats + 1152);
  bin_fin<<<256, 256, 0, stream>>>(stats + 1152, g6, be6, thri + 576, 256, 512.0 * 64.0);
  binpool_mm<16, 256><<<256, 256, 0, stream>>>((const int*)raw, thri + 576, A6);

  head_kern<<<512, 64, 0, stream>>>(A6, fcw, fcb, fcout);
  bn1d_kern<<<1, 640, 0, stream>>>(fcout, g7, be7, out);
}